// Round 1
// 1197.350 us; speedup vs baseline: 1.0929x; 1.0929x over previous
//
#include <hip/hip_runtime.h>
#include <hip/hip_bf16.h>
#include <math.h>

using bf16 = __hip_bfloat16;

typedef __bf16 bf16x4 __attribute__((ext_vector_type(4)));
typedef __bf16 bf16x8 __attribute__((ext_vector_type(8)));
typedef float  floatx4 __attribute__((ext_vector_type(4)));

__device__ __forceinline__ float b2f(bf16 x) { return __bfloat162float(x); }
__device__ __forceinline__ bf16  f2b(float x) { return __float2bfloat16(x); }

// ---------------------------------------------------------------------------
// Batched fp32 -> bf16 downcast. Up to 8 (src,dst,n) entries in one launch.
// grid.y = entry index; grid.x covers the largest entry; 4 elems/thread.
// ---------------------------------------------------------------------------
struct DcEnt { const float* s; __bf16* d; int n; };
struct DcPack { DcEnt e[8]; };

__global__ void __launch_bounds__(256)
downcast_all(DcPack p, int n_ent)
{
    const int ei = blockIdx.y;
    if (ei >= n_ent) return;
    const DcEnt ent = p.e[ei];
    const int i4 = (blockIdx.x * 256 + threadIdx.x) * 4;
    if (i4 + 3 >= ent.n) {
        for (int i = i4; i < ent.n; ++i) ent.d[i] = (__bf16)ent.s[i];
        return;
    }
    float4 v = *(const float4*)(ent.s + i4);
    bf16x4 o = { (__bf16)v.x, (__bf16)v.y, (__bf16)v.z, (__bf16)v.w };
    *(bf16x4*)(ent.d + i4) = o;
}

// ---------------------------------------------------------------------------
// im2col + downcast for the patch-embed convs (kernel == stride, no pad).
// Source is the scrambled (N,B,C)-flat key/value tensor:
//   addr = (b*256 + (c>>1))*8192 + ((s&15)<<9) + ((c&1)<<8) + (s>>4),
//   s = h*64 + w,  h = oy*st + ky, w = ox*st + kx.
// Output: dst[m][k] bf16 row-major, m = b*(hw) + oy*w1 + ox, k = c*st^2 + ky*st + kx.
// One thread per 8 consecutive k (16B store).
// ---------------------------------------------------------------------------
__global__ void __launch_bounds__(256)
im2col(const float* __restrict__ src, __bf16* __restrict__ dst,
       int hw_bits, int w1_bits, int ks_bits, int kbits)
{
    const int gid = blockIdx.x * 256 + threadIdx.x;
    const int m  = gid >> (kbits - 3);
    const int k0 = (gid & ((1 << (kbits - 3)) - 1)) << 3;

    const int b   = m >> hw_bits;
    const int pos = m & ((1 << hw_bits) - 1);
    const int oy  = pos >> w1_bits;
    const int ox  = pos & ((1 << w1_bits) - 1);
    const int spos = ((oy << ks_bits) << 6) + (ox << ks_bits);  // st*(h-part)+st*ox

    bf16x8 o;
#pragma unroll
    for (int e = 0; e < 8; ++e) {
        int k  = k0 + e;
        int c  = k >> (2 * ks_bits);
        int rk = k & ((1 << (2 * ks_bits)) - 1);
        int ky = rk >> ks_bits;
        int kx = rk & ((1 << ks_bits) - 1);
        int s  = spos + (ky << 6) + kx;
        size_t idx = (size_t)(b * 256 + (c >> 1)) * 8192 +
                     ((s & 15) << 9) + ((c & 1) << 8) + (s >> 4);
        o[e] = (__bf16)src[idx];
    }
    *(bf16x8*)(dst + (size_t)m * (1 << kbits) + k0) = o;
}

// ---------------------------------------------------------------------------
// MFMA GEMM: C[M,N] = A[M,K] @ B[N,K]^T (+bias). A,B bf16 row-major,
// fp32 accumulate. BM=128, BK=64, BN in {64,128}. 256 threads / 4 waves,
// wave grid 2x2, wave tile 64 x BN/2. Grid: x = m-tile, y = n-tile
// (same-XCD blocks share A tiles -> L2 reuse; grid.x % 8 == 0 keeps
// same-x, different-y blocks on one XCD).
// MFMA 16x16x32 layouts (validated in-codebase by attn_mfma):
//   A/B-frag: row = lane&15, k = quad*8 + j (16B contiguous)
//   C/D: col = lane&15, row = quad*4 + reg
// ---------------------------------------------------------------------------
template <int BN, typename OutT>
__global__ void __launch_bounds__(256)
mgemm(const __bf16* __restrict__ A, const __bf16* __restrict__ B,
      const float* __restrict__ bias, OutT* __restrict__ C,
      int N, int K)
{
    constexpr int BM = 128, BK = 64;
    constexpr int PK = BK + 8;            // 144B rows: 16B-aligned, conflict-benign
    constexpr int NI = BN / 32;           // n-frags per wave
    __shared__ __bf16 Asl[BM * PK];
    __shared__ __bf16 Bsl[BN * PK];

    const int tid  = threadIdx.x;
    const int w    = tid >> 6, lane = tid & 63;
    const int quad = lane >> 4, l16 = lane & 15;
    const int wm   = (w >> 1) * 64, wn = (w & 1) * (BN / 2);
    const int m0   = blockIdx.x * BM, n0 = blockIdx.y * BN;

    floatx4 acc[4][NI];
#pragma unroll
    for (int mi = 0; mi < 4; ++mi)
#pragma unroll
        for (int ni = 0; ni < NI; ++ni)
            acc[mi][ni] = (floatx4){0.f, 0.f, 0.f, 0.f};

    for (int k0 = 0; k0 < K; k0 += BK) {
        // stage A: 128x64 bf16 = 1024 16B-chunks, 4 per thread, coalesced
#pragma unroll
        for (int i = 0; i < (BM * BK / 8) / 256; ++i) {
            int idx = (i * 256 + tid) * 8;
            int m = idx >> 6, kk = idx & 63;
            *(bf16x8*)&Asl[m * PK + kk] =
                *(const bf16x8*)&A[(size_t)(m0 + m) * K + k0 + kk];
        }
        // stage B
#pragma unroll
        for (int i = 0; i < (BN * BK / 8) / 256; ++i) {
            int idx = (i * 256 + tid) * 8;
            int n = idx >> 6, kk = idx & 63;
            *(bf16x8*)&Bsl[n * PK + kk] =
                *(const bf16x8*)&B[(size_t)(n0 + n) * K + k0 + kk];
        }
        __syncthreads();
#pragma unroll
        for (int ks = 0; ks < 2; ++ks) {
            bf16x8 af[4], bf[NI];
#pragma unroll
            for (int mi = 0; mi < 4; ++mi)
                af[mi] = *(const bf16x8*)&Asl[(wm + mi * 16 + l16) * PK + ks * 32 + quad * 8];
#pragma unroll
            for (int ni = 0; ni < NI; ++ni)
                bf[ni] = *(const bf16x8*)&Bsl[(wn + ni * 16 + l16) * PK + ks * 32 + quad * 8];
#pragma unroll
            for (int mi = 0; mi < 4; ++mi)
#pragma unroll
                for (int ni = 0; ni < NI; ++ni)
                    acc[mi][ni] = __builtin_amdgcn_mfma_f32_16x16x32_bf16(
                        af[mi], bf[ni], acc[mi][ni], 0, 0, 0);
        }
        __syncthreads();
    }

#pragma unroll
    for (int mi = 0; mi < 4; ++mi)
#pragma unroll
        for (int r = 0; r < 4; ++r) {
            int row = m0 + wm + mi * 16 + quad * 4 + r;
#pragma unroll
            for (int ni = 0; ni < NI; ++ni) {
                int col = n0 + wn + ni * 16 + l16;
                float v = acc[mi][ni][r];
                if (bias) v += bias[col];
                C[(size_t)row * N + col] = (OutT)v;
            }
        }
}

// ---------------------------------------------------------------------------
// Split-K MFMA GEMM: identical compute structure to mgemm, but blockIdx.z
// selects a contiguous K-chunk of length KC and writes fp32 partials to
// P[z*mn + row*N + col] (no bias). Purpose: the SR1 conv GEMM is M=4096,
// N=512 -> only 256 blocks = 1 wave/SIMD = latency-bound (Occupancy 11%,
// all pipes <12%). SK=4 -> 1024 blocks = 4 waves/SIMD.
// ---------------------------------------------------------------------------
template <int BN>
__global__ void __launch_bounds__(256)
mgemm_sk(const __bf16* __restrict__ A, const __bf16* __restrict__ B,
         float* __restrict__ P, int N, int K, int KC, size_t mn)
{
    constexpr int BM = 128, BK = 64;
    constexpr int PK = BK + 8;
    constexpr int NI = BN / 32;
    __shared__ __bf16 Asl[BM * PK];
    __shared__ __bf16 Bsl[BN * PK];

    const int tid  = threadIdx.x;
    const int w    = tid >> 6, lane = tid & 63;
    const int quad = lane >> 4, l16 = lane & 15;
    const int wm   = (w >> 1) * 64, wn = (w & 1) * (BN / 2);
    const int m0   = blockIdx.x * BM, n0 = blockIdx.y * BN;
    const int kbeg = blockIdx.z * KC;

    floatx4 acc[4][NI];
#pragma unroll
    for (int mi = 0; mi < 4; ++mi)
#pragma unroll
        for (int ni = 0; ni < NI; ++ni)
            acc[mi][ni] = (floatx4){0.f, 0.f, 0.f, 0.f};

    for (int k0 = kbeg; k0 < kbeg + KC; k0 += BK) {
#pragma unroll
        for (int i = 0; i < (BM * BK / 8) / 256; ++i) {
            int idx = (i * 256 + tid) * 8;
            int m = idx >> 6, kk = idx & 63;
            *(bf16x8*)&Asl[m * PK + kk] =
                *(const bf16x8*)&A[(size_t)(m0 + m) * K + k0 + kk];
        }
#pragma unroll
        for (int i = 0; i < (BN * BK / 8) / 256; ++i) {
            int idx = (i * 256 + tid) * 8;
            int n = idx >> 6, kk = idx & 63;
            *(bf16x8*)&Bsl[n * PK + kk] =
                *(const bf16x8*)&B[(size_t)(n0 + n) * K + k0 + kk];
        }
        __syncthreads();
#pragma unroll
        for (int ks = 0; ks < 2; ++ks) {
            bf16x8 af[4], bf[NI];
#pragma unroll
            for (int mi = 0; mi < 4; ++mi)
                af[mi] = *(const bf16x8*)&Asl[(wm + mi * 16 + l16) * PK + ks * 32 + quad * 8];
#pragma unroll
            for (int ni = 0; ni < NI; ++ni)
                bf[ni] = *(const bf16x8*)&Bsl[(wn + ni * 16 + l16) * PK + ks * 32 + quad * 8];
#pragma unroll
            for (int mi = 0; mi < 4; ++mi)
#pragma unroll
                for (int ni = 0; ni < NI; ++ni)
                    acc[mi][ni] = __builtin_amdgcn_mfma_f32_16x16x32_bf16(
                        af[mi], bf[ni], acc[mi][ni], 0, 0, 0);
        }
        __syncthreads();
    }

    float* Pz = P + (size_t)blockIdx.z * mn;
#pragma unroll
    for (int mi = 0; mi < 4; ++mi)
#pragma unroll
        for (int r = 0; r < 4; ++r) {
            int row = m0 + wm + mi * 16 + quad * 4 + r;
#pragma unroll
            for (int ni = 0; ni < NI; ++ni) {
                int col = n0 + wn + ni * 16 + l16;
                Pz[(size_t)row * N + col] = acc[mi][ni][r];
            }
        }
}

// ---------------------------------------------------------------------------
// Split-K reduce: out[i] = bf16( sum_z P[z*mn + i] + bias[i & nmask] ).
// 4 fp32 elems / thread (vectorized). nmask = N-1 (N power of two, 4 | N).
// ---------------------------------------------------------------------------
__global__ void __launch_bounds__(256)
sk_reduce(const float* __restrict__ P, const float* __restrict__ bias,
          __bf16* __restrict__ out, size_t mn, int nsplit, int nmask)
{
    const size_t i = ((size_t)blockIdx.x * 256 + threadIdx.x) * 4;
    if (i >= mn) return;
    float4 s = *(const float4*)(P + i);
    for (int z = 1; z < nsplit; ++z) {
        float4 t = *(const float4*)(P + (size_t)z * mn + i);
        s.x += t.x; s.y += t.y; s.z += t.z; s.w += t.w;
    }
    if (bias) {
        const int c = (int)(i & (size_t)nmask);
        s.x += bias[c]; s.y += bias[c + 1]; s.z += bias[c + 2]; s.w += bias[c + 3];
    }
    bf16x4 o = { (__bf16)s.x, (__bf16)s.y, (__bf16)s.z, (__bf16)s.w };
    *(bf16x4*)(out + i) = o;
}

// ---------------------------------------------------------------------------
// In-place LayerNorm(C=512) + exact GELU on bf16 data, fp32 params.
// ---------------------------------------------------------------------------
__global__ void __launch_bounds__(256)
ln_gelu(bf16* __restrict__ data, const float* __restrict__ w, const float* __restrict__ bp)
{
    __shared__ float red[256];
    const int tid = threadIdx.x;
    const size_t base = (size_t)blockIdx.x * 512;
    float x0 = b2f(data[base + tid]);
    float x1 = b2f(data[base + 256 + tid]);

    red[tid] = x0 + x1;
    __syncthreads();
#pragma unroll
    for (int off = 128; off > 0; off >>= 1) {
        if (tid < off) red[tid] += red[tid + off];
        __syncthreads();
    }
    float mu = red[0] * (1.0f / 512.0f);
    __syncthreads();

    float d0 = x0 - mu, d1 = x1 - mu;
    red[tid] = d0 * d0 + d1 * d1;
    __syncthreads();
#pragma unroll
    for (int off = 128; off > 0; off >>= 1) {
        if (tid < off) red[tid] += red[tid + off];
        __syncthreads();
    }
    float rstd = rsqrtf(red[0] * (1.0f / 512.0f) + 1e-5f);

    float y0 = d0 * rstd * w[tid] + bp[tid];
    float y1 = d1 * rstd * w[256 + tid] + bp[256 + tid];
    y0 = 0.5f * y0 * (1.0f + erff(y0 * 0.70710678118654752f));
    y1 = 0.5f * y1 * (1.0f + erff(y1 * 0.70710678118654752f));
    data[base + tid]       = f2b(y0);
    data[base + 256 + tid] = f2b(y1);
}

// ---------------------------------------------------------------------------
// v + depthwise 3x3 (pad 1) residual, layout (B*hw, 256). bf16 data, fp32 wts.
// ---------------------------------------------------------------------------
__global__ void __launch_bounds__(256)
local_res(const bf16* __restrict__ v, const float* __restrict__ lw,
          const float* __restrict__ lb, bf16* __restrict__ outp,
          int hw_bits, int w1_bits)
{
    const int idx = blockIdx.x * 256 + threadIdx.x;
    const int c   = idx & 255;
    const int pix = (idx >> 8) & ((1 << hw_bits) - 1);
    const int b   = idx >> (8 + hw_bits);
    const int w1  = 1 << w1_bits;
    const int h1  = 1 << (hw_bits - w1_bits);
    const int y = pix >> w1_bits, x = pix & (w1 - 1);

    float acc = b2f(v[idx]) + lb[c];
#pragma unroll
    for (int ky = 0; ky < 3; ++ky) {
        int yy = y + ky - 1;
        if (yy < 0 || yy >= h1) continue;
#pragma unroll
        for (int kx = 0; kx < 3; ++kx) {
            int xx = x + kx - 1;
            if (xx < 0 || xx >= w1) continue;
            acc += lw[c * 9 + ky * 3 + kx] *
                   b2f(v[(((b << hw_bits) + (yy << w1_bits) + xx) << 8) + c]);
        }
    }
    outp[idx] = f2b(acc);
}

// ---------------------------------------------------------------------------
// MFMA attention (unchanged — validated).
// ---------------------------------------------------------------------------
__global__ void __launch_bounds__(256)
attn_mfma(const bf16* __restrict__ qmat, const bf16* __restrict__ kmat,
          const bf16* __restrict__ vmat, bf16* __restrict__ x,
          int Nk, int hoff, int xoff)
{
    __shared__ __bf16 lds_vt[64][40];
    __shared__ __bf16 lds_p[4][16][40];

    const int bid = blockIdx.x;
    const int qt = bid & 15;
    const int h  = (bid >> 4) & 3;
    const int b  = bid >> 6;
    const int tid = threadIdx.x;
    const int w = tid >> 6, lane = tid & 63;
    const int quad = lane >> 4, l16 = lane & 15;

    const int qrow = b * 1024 + qt * 64 + w * 16 + l16;
    const __bf16* qp = (const __bf16*)qmat + (size_t)qrow * 512 + (hoff + h) * 64 + quad * 8;
    const bf16x8 qf0 = *(const bf16x8*)qp;
    const bf16x8 qf1 = *(const bf16x8*)(qp + 32);

    floatx4 acc_o[4];
#pragma unroll
    for (int nt = 0; nt < 4; ++nt) acc_o[nt] = (floatx4){0.f, 0.f, 0.f, 0.f};
    float rs[4] = {0.f, 0.f, 0.f, 0.f};

    const size_t kvbase = (size_t)b * Nk * 256 + (size_t)h * 64;

    for (int j0 = 0; j0 < Nk; j0 += 32) {
        __syncthreads();
        {
            const int jr = tid >> 3;
            const int dc = (tid & 7) * 8;
            bf16x8 vv = *(const bf16x8*)((const __bf16*)vmat + kvbase +
                                         (size_t)(j0 + jr) * 256 + dc);
#pragma unroll
            for (int e = 0; e < 8; ++e)
                lds_vt[dc + e][jr] = vv[e];
        }
        __syncthreads();

#pragma unroll
        for (int jh = 0; jh < 2; ++jh) {
            const __bf16* kp = (const __bf16*)kmat + kvbase +
                               (size_t)(j0 + jh * 16 + l16) * 256 + quad * 8;
            bf16x8 kf0 = *(const bf16x8*)kp;
            bf16x8 kf1 = *(const bf16x8*)(kp + 32);
            floatx4 s = (floatx4){0.f, 0.f, 0.f, 0.f};
            s = __builtin_amdgcn_mfma_f32_16x16x32_bf16(qf0, kf0, s, 0, 0, 0);
            s = __builtin_amdgcn_mfma_f32_16x16x32_bf16(qf1, kf1, s, 0, 0, 0);
#pragma unroll
            for (int r = 0; r < 4; ++r) {
                float p = __expf(s[r] * 0.125f);
                rs[r] += p;
                lds_p[w][quad * 4 + r][jh * 16 + l16] = (__bf16)p;
            }
        }
        bf16x8 pf = *(const bf16x8*)&lds_p[w][l16][quad * 8];
#pragma unroll
        for (int nt = 0; nt < 4; ++nt) {
            bf16x8 vf = *(const bf16x8*)&lds_vt[nt * 16 + l16][quad * 8];
            acc_o[nt] = __builtin_amdgcn_mfma_f32_16x16x32_bf16(pf, vf, acc_o[nt], 0, 0, 0);
        }
    }

#pragma unroll
    for (int r = 0; r < 4; ++r) {
        float v = rs[r];
        v += __shfl_xor(v, 1);
        v += __shfl_xor(v, 2);
        v += __shfl_xor(v, 4);
        v += __shfl_xor(v, 8);
        rs[r] = v;
    }

    const int mg = qt * 64 + w * 16 + quad * 4;
#pragma unroll
    for (int r = 0; r < 4; ++r) {
        const float inv = 1.0f / rs[r];
        __bf16* xr = (__bf16*)x + (size_t)(b * 1024 + mg + r) * 512 + xoff + h * 64;
#pragma unroll
        for (int nt = 0; nt < 4; ++nt)
            xr[nt * 16 + l16] = (__bf16)(acc_o[nt][r] * inv);
    }
}

// ---------------------------------------------------------------------------
extern "C" void kernel_launch(void* const* d_in, const int* in_sizes, int n_in,
                              void* d_out, int out_size, void* d_ws, size_t ws_size,
                              hipStream_t stream)
{
    const float* query   = (const float*)d_in[0];
    const float* key     = (const float*)d_in[1];
    const float* value   = (const float*)d_in[2];
    const float* q_w     = (const float*)d_in[5];
    const float* sr1_w   = (const float*)d_in[6];
    const float* sr1_b   = (const float*)d_in[7];
    const float* norm1_w = (const float*)d_in[8];
    const float* norm1_b = (const float*)d_in[9];
    const float* sr2_w   = (const float*)d_in[10];
    const float* sr2_b   = (const float*)d_in[11];
    const float* norm2_w = (const float*)d_in[12];
    const float* norm2_b = (const float*)d_in[13];
    const float* k1_w    = (const float*)d_in[14];
    /* v1_w = d_in[15] unused: reference (faithfully) uses k1_w for v1 */
    const float* k2_w    = (const float*)d_in[16];
    const float* v2_w    = (const float*)d_in[17];
    const float* lc1_w   = (const float*)d_in[18];
    const float* lc1_b   = (const float*)d_in[19];
    const float* lc2_w   = (const float*)d_in[20];
    const float* lc2_b   = (const float*)d_in[21];
    const float* proj_w  = (const float*)d_in[22];
    const float* proj_b  = (const float*)d_in[23];
    float* out = (float*)d_out;

    // ---- workspace map (MiB offsets), peak ~116 MiB -----------------------
    char* base = (char*)d_ws;
    const size_t MiB = 1024 * 1024;
    __bf16* S     = (__bf16*)(base + 0 * MiB);    // 64 MiB: im2col scratch, then:
    __bf16* qproj = S;                            //   S+0  : 16 MiB (16384x512)
    __bf16* k1    = (__bf16*)(base + 16 * MiB);   //   S+16 :  2 MiB (4096x256)
    __bf16* v1    = (__bf16*)(base + 18 * MiB);   //   S+18 :  2 MiB
    __bf16* k2    = (__bf16*)(base + 20 * MiB);   //   S+20 :  8 MiB (16384x256)
    __bf16* v2    = (__bf16*)(base + 28 * MiB);   //   S+28 :  8 MiB
    __bf16* qbf   = (__bf16*)(base + 36 * MiB);   //   S+36 : 16 MiB (query bf16)
    __bf16* c1k   = (__bf16*)(base + 64 * MiB);   //  4 MiB (4096x512)
    __bf16* c1v   = (__bf16*)(base + 68 * MiB);   //  4 MiB
    __bf16* c2k   = (__bf16*)(base + 72 * MiB);   // 16 MiB (16384x512)
    __bf16* c2v   = (__bf16*)(base + 88 * MiB);   // 16 MiB
    float*  skp   = (float*)(base + 72 * MiB);    // 32 MiB: split-K partials
                                                  // (c2k/c2v region — dead
                                                  //  during sr1 GEMMs)
    __bf16* wq    = (__bf16*)(base + 104 * MiB);  // 0.5 MiB (512x512)
    __bf16* wsr1  = (__bf16*)(base + 104 * MiB + 524288);            // 8 MiB
    __bf16* wsr2  = (__bf16*)(base + 112 * MiB + 524288);            // 2 MiB
    __bf16* wk1   = (__bf16*)(base + 114 * MiB + 524288);            // 0.25
    __bf16* wk2   = (__bf16*)(base + 114 * MiB + 786432);            // 0.25
    __bf16* wv2   = (__bf16*)(base + 115 * MiB);                     // 0.25
    __bf16* wproj = (__bf16*)(base + 115 * MiB + 262144);            // 0.5
    __bf16* v1r   = c1k;   // alias: c1k dead after k1 head-proj
    __bf16* v2r   = c2v;   // alias: c2v dead after v2 head-proj
    __bf16* xbuf  = c2k;   // alias: c2k dead after k2 head-proj

    dim3 blk(256);

    // 1) weights -> bf16 (one launch)
    {
        DcPack p;
        p.e[0] = { q_w,    wq,    512 * 512 };
        p.e[1] = { sr1_w,  wsr1,  512 * 8192 };
        p.e[2] = { sr2_w,  wsr2,  512 * 2048 };
        p.e[3] = { k1_w,   wk1,   256 * 512 };
        p.e[4] = { k2_w,   wk2,   256 * 512 };
        p.e[5] = { v2_w,   wv2,   256 * 512 };
        p.e[6] = { proj_w, wproj, 512 * 512 };
        p.e[7] = { nullptr, nullptr, 0 };
        int maxb = (512 * 8192 / 4 + 255) / 256;
        downcast_all<<<dim3(maxb, 7), blk, 0, stream>>>(p, 7);
    }

    // 2) convs. SR1 GEMM (M=4096,N=512,K=8192) was latency-bound at 256
    //    blocks (1 wave/SIMD, Occupancy 11%, MfmaUtil 11%): split-K=4 ->
    //    1024 blocks (4 waves/SIMD), fp32 partials in skp, fused reduce.
    const size_t mn1 = 4096 * 512;
    im2col<<<dim3(16384), blk, 0, stream>>>(key, S, 8, 4, 2, 13);
    mgemm_sk<64><<<dim3(32, 8, 4), blk, 0, stream>>>(S, wsr1, skp, 512, 8192, 2048, mn1);
    sk_reduce<<<dim3(mn1 / 1024), blk, 0, stream>>>(skp, sr1_b, c1k, mn1, 4, 511);
    im2col<<<dim3(16384), blk, 0, stream>>>(value, S, 8, 4, 2, 13);
    mgemm_sk<64><<<dim3(32, 8, 4), blk, 0, stream>>>(S, wsr1, skp, 512, 8192, 2048, mn1);
    sk_reduce<<<dim3(mn1 / 1024), blk, 0, stream>>>(skp, sr1_b, c1v, mn1, 4, 511);
    //    SR2 GEMMs (M=16384): BN=64 -> 1024 blocks (was 512).
    im2col<<<dim3(16384), blk, 0, stream>>>(key, S, 10, 5, 1, 11);
    mgemm<64, __bf16><<<dim3(128, 8), blk, 0, stream>>>(S, wsr2, sr2_b, c2k, 512, 2048);
    im2col<<<dim3(16384), blk, 0, stream>>>(value, S, 10, 5, 1, 11);
    mgemm<64, __bf16><<<dim3(128, 8), blk, 0, stream>>>(S, wsr2, sr2_b, c2v, 512, 2048);

    // 3) query -> bf16, then q projection (into S, now free). BN=64 -> 1024 blocks.
    {
        DcPack p;
        p.e[0] = { query, qbf, 16384 * 512 };
        downcast_all<<<dim3(16384 * 512 / 1024, 1), blk, 0, stream>>>(p, 1);
    }
    mgemm<64, __bf16><<<dim3(128, 8), blk, 0, stream>>>(qbf, wq, nullptr, qproj, 512, 512);

    // 4) LayerNorm + GELU (in place)
    ln_gelu<<<dim3(4096),  blk, 0, stream>>>((bf16*)c1k, norm1_w, norm1_b);
    ln_gelu<<<dim3(4096),  blk, 0, stream>>>((bf16*)c1v, norm1_w, norm1_b);
    ln_gelu<<<dim3(16384), blk, 0, stream>>>((bf16*)c2k, norm2_w, norm2_b);
    ln_gelu<<<dim3(16384), blk, 0, stream>>>((bf16*)c2v, norm2_w, norm2_b);

    // 5) head projections (v1 uses k1_w — faithful to source). c2: BN=64.
    mgemm<64, __bf16><<<dim3(32, 4),  blk, 0, stream>>>(c1k, wk1, nullptr, k1, 256, 512);
    mgemm<64, __bf16><<<dim3(32, 4),  blk, 0, stream>>>(c1v, wk1, nullptr, v1, 256, 512);
    mgemm<64, __bf16><<<dim3(128, 4), blk, 0, stream>>>(c2k, wk2, nullptr, k2, 256, 512);
    mgemm<64, __bf16><<<dim3(128, 4), blk, 0, stream>>>(c2v, wv2, nullptr, v2, 256, 512);

    // 6) depthwise 3x3 residual
    local_res<<<dim3(4096),  blk, 0, stream>>>((bf16*)v1, lc1_w, lc1_b, (bf16*)v1r, 8, 4);
    local_res<<<dim3(16384), blk, 0, stream>>>((bf16*)v2, lc2_w, lc2_b, (bf16*)v2r, 10, 5);

    // 7) MFMA attention
    attn_mfma<<<dim3(1024), blk, 0, stream>>>((bf16*)qproj, (bf16*)k1, (bf16*)v1r,
                                              (bf16*)xbuf, 256, 0, 0);
    attn_mfma<<<dim3(1024), blk, 0, stream>>>((bf16*)qproj, (bf16*)k2, (bf16*)v2r,
                                              (bf16*)xbuf, 1024, 4, 256);

    // 8) out = x @ proj_w^T + proj_b (fp32 out). BN=64 -> 1024 blocks.
    mgemm<64, float><<<dim3(128, 8), blk, 0, stream>>>(xbuf, wproj, proj_b, out, 512, 512);
}

// Round 4
// 1021.340 us; speedup vs baseline: 1.2812x; 1.1723x over previous
//
#include <hip/hip_runtime.h>
#include <hip/hip_bf16.h>
#include <math.h>

using bf16 = __hip_bfloat16;

typedef __bf16 bf16x4 __attribute__((ext_vector_type(4)));
typedef __bf16 bf16x8 __attribute__((ext_vector_type(8)));
typedef float  floatx4 __attribute__((ext_vector_type(4)));

__device__ __forceinline__ float b2f(bf16 x) { return __bfloat162float(x); }
__device__ __forceinline__ bf16  f2b(float x) { return __float2bfloat16(x); }

// LDS index swizzle: XOR bits [11:15) into bank bits [2:6). Keeps aligned
// 4-element (8B) groups contiguous (bits [0:2) untouched), breaks the
// x512-element stride conflicts of the im2col gather.
__device__ __forceinline__ int swz(int i) { return i ^ (((i >> 11) & 15) << 2); }

// ---------------------------------------------------------------------------
// Batched fp32 -> bf16 downcast. Up to 8 (src,dst,n) entries in one launch.
// ---------------------------------------------------------------------------
struct DcEnt { const float* s; __bf16* d; int n; };
struct DcPack { DcEnt e[8]; };

__global__ void __launch_bounds__(256)
downcast_all(DcPack p, int n_ent)
{
    const int ei = blockIdx.y;
    if (ei >= n_ent) return;
    const DcEnt ent = p.e[ei];
    const int i4 = (blockIdx.x * 256 + threadIdx.x) * 4;
    if (i4 + 3 >= ent.n) {
        for (int i = i4; i < ent.n; ++i) ent.d[i] = (__bf16)ent.s[i];
        return;
    }
    float4 v = *(const float4*)(ent.s + i4);
    bf16x4 o = { (__bf16)v.x, (__bf16)v.y, (__bf16)v.z, (__bf16)v.w };
    *(bf16x4*)(ent.d + i4) = o;
}

// ---------------------------------------------------------------------------
// Source-coalesced im2col for the 4x4/stride-4 conv (sr1).
// Source scramble (validated): elem (b, c, s) at
//   (b*256 + (c>>1))*8192 + ((s&15)<<9) + ((c&1)<<8) + (s>>4),  s = h*64+w.
// One block = one (b, c2=c>>1) slab = 8192 contiguous floats. Its dest is a
// dense (256 rows x 32 cols) tile of A: rows m = b*256 + oy*16 + ox,
// cols k = c2*32 + (cc*16 + ky*4 + kx). Stream slab coalesced -> LDS (bf16,
// swizzled), then 4 passes of 64 rows: lanes 4t..4t+3 emit one 64B row.
// Replaces the scattered-gather version (8x 4B loads/thread, 107 us,
// transaction-bound: all pipes <19%).
// ---------------------------------------------------------------------------
__global__ void __launch_bounds__(256)
im2col_sr1(const float* __restrict__ src, __bf16* __restrict__ dst)
{
    __shared__ __bf16 lds[8192];
    const int b  = blockIdx.x >> 8;
    const int c2 = blockIdx.x & 255;
    const int tid = threadIdx.x;
    const float* sp = src + ((size_t)(b * 256 + c2) << 13);

#pragma unroll
    for (int i = 0; i < 8; ++i) {
        int idx = (i * 256 + tid) * 4;
        float4 v = *(const float4*)(sp + idx);
        int o = swz(idx);
        lds[o + 0] = (__bf16)v.x; lds[o + 1] = (__bf16)v.y;
        lds[o + 2] = (__bf16)v.z; lds[o + 3] = (__bf16)v.w;
    }
    __syncthreads();

    const int j = tid & 3;
#pragma unroll
    for (int p = 0; p < 4; ++p) {
        int r  = p * 64 + (tid >> 2);
        int oy = r >> 4, ox = r & 15;
        bf16x8 o;
#pragma unroll
        for (int u = 0; u < 8; ++u) {
            int e  = j * 8 + u;                 // col within tile, [0,32)
            int cc = e >> 4, ky = (e >> 2) & 3, kx = e & 3;
            int i  = (4 * (ox & 3) + kx) * 512 + cc * 256 +
                     (4 * oy + ky) * 4 + (ox >> 2);
            o[u] = lds[swz(i)];
        }
        *(bf16x8*)(dst + ((size_t)(b * 256 + r) << 13) + c2 * 32 + j * 8) = o;
    }
}

// ---------------------------------------------------------------------------
// Source-coalesced im2col for the 2x2/stride-2 conv (sr2). K=2048.
// One (b,c2) slab only yields 8 cols (16B) per row, so group 4 consecutive
// slabs per block (cg = c2>>2): 32768 floats contiguous in, dense
// (1024 rows x 32 cols) tile out (rows m = b*1024 + oy*32 + ox, cols
// k = cg*32 + (q*8 + cc*4 + ky*2 + kx), slab q == store slot j).
// 256 threads (all session-validated kernels use 256), 64 KiB LDS.
// ---------------------------------------------------------------------------
__global__ void __launch_bounds__(256)
im2col_sr2(const float* __restrict__ src, __bf16* __restrict__ dst)
{
    __shared__ __bf16 lds[32768];
    const int b  = blockIdx.x >> 6;
    const int cg = blockIdx.x & 63;
    const int tid = threadIdx.x;
    const float* sp = src + ((size_t)(b * 256 + cg * 4) << 13);

#pragma unroll
    for (int i = 0; i < 32; ++i) {
        int idx = (i * 256 + tid) * 4;
        float4 v = *(const float4*)(sp + idx);
        int o = swz(idx);
        lds[o + 0] = (__bf16)v.x; lds[o + 1] = (__bf16)v.y;
        lds[o + 2] = (__bf16)v.z; lds[o + 3] = (__bf16)v.w;
    }
    __syncthreads();

    const int j = tid & 3;                      // slot == slab q
#pragma unroll
    for (int p = 0; p < 16; ++p) {
        int r  = p * 64 + (tid >> 2);
        int oy = r >> 5, ox = r & 31;
        bf16x8 o;
#pragma unroll
        for (int u = 0; u < 8; ++u) {
            int cc = (u >> 2) & 1, ky = (u >> 1) & 1, kx = u & 1;
            int i  = j * 8192 + (2 * (ox & 7) + kx) * 512 + cc * 256 +
                     (2 * oy + ky) * 4 + (ox >> 3);
            o[u] = lds[swz(i)];
        }
        *(bf16x8*)(dst + ((size_t)(b * 1024 + r) << 11) + cg * 32 + j * 8) = o;
    }
}

// ---------------------------------------------------------------------------
// MFMA GEMM: C[M,N] = A[M,K] @ B[N,K]^T (+bias). A,B bf16 row-major,
// fp32 accumulate. BM=128, BK=64, BN in {64,128}. 256 threads / 4 waves,
// wave grid 2x2, wave tile 64 x BN/2.
// MFMA 16x16x32 layouts (validated in-codebase by attn_mfma):
//   A/B-frag: row = lane&15, k = quad*8 + j (16B contiguous)
//   C/D: col = lane&15, row = quad*4 + reg
// ---------------------------------------------------------------------------
template <int BN, typename OutT>
__global__ void __launch_bounds__(256)
mgemm(const __bf16* __restrict__ A, const __bf16* __restrict__ B,
      const float* __restrict__ bias, OutT* __restrict__ C,
      int N, int K)
{
    constexpr int BM = 128, BK = 64;
    constexpr int PK = BK + 8;            // 144B rows: 16B-aligned, conflict-benign
    constexpr int NI = BN / 32;           // n-frags per wave
    __shared__ __bf16 Asl[BM * PK];
    __shared__ __bf16 Bsl[BN * PK];

    const int tid  = threadIdx.x;
    const int w    = tid >> 6, lane = tid & 63;
    const int quad = lane >> 4, l16 = lane & 15;
    const int wm   = (w >> 1) * 64, wn = (w & 1) * (BN / 2);
    const int m0   = blockIdx.x * BM, n0 = blockIdx.y * BN;

    floatx4 acc[4][NI];
#pragma unroll
    for (int mi = 0; mi < 4; ++mi)
#pragma unroll
        for (int ni = 0; ni < NI; ++ni)
            acc[mi][ni] = (floatx4){0.f, 0.f, 0.f, 0.f};

    for (int k0 = 0; k0 < K; k0 += BK) {
#pragma unroll
        for (int i = 0; i < (BM * BK / 8) / 256; ++i) {
            int idx = (i * 256 + tid) * 8;
            int m = idx >> 6, kk = idx & 63;
            *(bf16x8*)&Asl[m * PK + kk] =
                *(const bf16x8*)&A[(size_t)(m0 + m) * K + k0 + kk];
        }
#pragma unroll
        for (int i = 0; i < (BN * BK / 8) / 256; ++i) {
            int idx = (i * 256 + tid) * 8;
            int n = idx >> 6, kk = idx & 63;
            *(bf16x8*)&Bsl[n * PK + kk] =
                *(const bf16x8*)&B[(size_t)(n0 + n) * K + k0 + kk];
        }
        __syncthreads();
#pragma unroll
        for (int ks = 0; ks < 2; ++ks) {
            bf16x8 af[4], bf[NI];
#pragma unroll
            for (int mi = 0; mi < 4; ++mi)
                af[mi] = *(const bf16x8*)&Asl[(wm + mi * 16 + l16) * PK + ks * 32 + quad * 8];
#pragma unroll
            for (int ni = 0; ni < NI; ++ni)
                bf[ni] = *(const bf16x8*)&Bsl[(wn + ni * 16 + l16) * PK + ks * 32 + quad * 8];
#pragma unroll
            for (int mi = 0; mi < 4; ++mi)
#pragma unroll
                for (int ni = 0; ni < NI; ++ni)
                    acc[mi][ni] = __builtin_amdgcn_mfma_f32_16x16x32_bf16(
                        af[mi], bf[ni], acc[mi][ni], 0, 0, 0);
        }
        __syncthreads();
    }

#pragma unroll
    for (int mi = 0; mi < 4; ++mi)
#pragma unroll
        for (int r = 0; r < 4; ++r) {
            int row = m0 + wm + mi * 16 + quad * 4 + r;
#pragma unroll
            for (int ni = 0; ni < NI; ++ni) {
                int col = n0 + wn + ni * 16 + l16;
                float v = acc[mi][ni][r];
                if (bias) v += bias[col];
                C[(size_t)row * N + col] = (OutT)v;
            }
        }
}

// ---------------------------------------------------------------------------
// Split-K MFMA GEMM (fp32 partials, no bias): the SR1 conv GEMM is
// M=4096, N=512 -> only 256 blocks = 1 wave/SIMD = latency-bound. SK=4 ->
// 1024 blocks = 4 waves/SIMD.
// ---------------------------------------------------------------------------
template <int BN>
__global__ void __launch_bounds__(256)
mgemm_sk(const __bf16* __restrict__ A, const __bf16* __restrict__ B,
         float* __restrict__ P, int N, int K, int KC, size_t mn)
{
    constexpr int BM = 128, BK = 64;
    constexpr int PK = BK + 8;
    constexpr int NI = BN / 32;
    __shared__ __bf16 Asl[BM * PK];
    __shared__ __bf16 Bsl[BN * PK];

    const int tid  = threadIdx.x;
    const int w    = tid >> 6, lane = tid & 63;
    const int quad = lane >> 4, l16 = lane & 15;
    const int wm   = (w >> 1) * 64, wn = (w & 1) * (BN / 2);
    const int m0   = blockIdx.x * BM, n0 = blockIdx.y * BN;
    const int kbeg = blockIdx.z * KC;

    floatx4 acc[4][NI];
#pragma unroll
    for (int mi = 0; mi < 4; ++mi)
#pragma unroll
        for (int ni = 0; ni < NI; ++ni)
            acc[mi][ni] = (floatx4){0.f, 0.f, 0.f, 0.f};

    for (int k0 = kbeg; k0 < kbeg + KC; k0 += BK) {
#pragma unroll
        for (int i = 0; i < (BM * BK / 8) / 256; ++i) {
            int idx = (i * 256 + tid) * 8;
            int m = idx >> 6, kk = idx & 63;
            *(bf16x8*)&Asl[m * PK + kk] =
                *(const bf16x8*)&A[(size_t)(m0 + m) * K + k0 + kk];
        }
#pragma unroll
        for (int i = 0; i < (BN * BK / 8) / 256; ++i) {
            int idx = (i * 256 + tid) * 8;
            int n = idx >> 6, kk = idx & 63;
            *(bf16x8*)&Bsl[n * PK + kk] =
                *(const bf16x8*)&B[(size_t)(n0 + n) * K + k0 + kk];
        }
        __syncthreads();
#pragma unroll
        for (int ks = 0; ks < 2; ++ks) {
            bf16x8 af[4], bf[NI];
#pragma unroll
            for (int mi = 0; mi < 4; ++mi)
                af[mi] = *(const bf16x8*)&Asl[(wm + mi * 16 + l16) * PK + ks * 32 + quad * 8];
#pragma unroll
            for (int ni = 0; ni < NI; ++ni)
                bf[ni] = *(const bf16x8*)&Bsl[(wn + ni * 16 + l16) * PK + ks * 32 + quad * 8];
#pragma unroll
            for (int mi = 0; mi < 4; ++mi)
#pragma unroll
                for (int ni = 0; ni < NI; ++ni)
                    acc[mi][ni] = __builtin_amdgcn_mfma_f32_16x16x32_bf16(
                        af[mi], bf[ni], acc[mi][ni], 0, 0, 0);
        }
        __syncthreads();
    }

    float* Pz = P + (size_t)blockIdx.z * mn;
#pragma unroll
    for (int mi = 0; mi < 4; ++mi)
#pragma unroll
        for (int r = 0; r < 4; ++r) {
            int row = m0 + wm + mi * 16 + quad * 4 + r;
#pragma unroll
            for (int ni = 0; ni < NI; ++ni) {
                int col = n0 + wn + ni * 16 + l16;
                Pz[(size_t)row * N + col] = acc[mi][ni][r];
            }
        }
}

// ---------------------------------------------------------------------------
// Split-K reduce: out[i] = bf16( sum_z P[z*mn + i] + bias[i & nmask] ).
// ---------------------------------------------------------------------------
__global__ void __launch_bounds__(256)
sk_reduce(const float* __restrict__ P, const float* __restrict__ bias,
          __bf16* __restrict__ out, size_t mn, int nsplit, int nmask)
{
    const size_t i = ((size_t)blockIdx.x * 256 + threadIdx.x) * 4;
    if (i >= mn) return;
    float4 s = *(const float4*)(P + i);
    for (int z = 1; z < nsplit; ++z) {
        float4 t = *(const float4*)(P + (size_t)z * mn + i);
        s.x += t.x; s.y += t.y; s.z += t.z; s.w += t.w;
    }
    if (bias) {
        const int c = (int)(i & (size_t)nmask);
        s.x += bias[c]; s.y += bias[c + 1]; s.z += bias[c + 2]; s.w += bias[c + 3];
    }
    bf16x4 o = { (__bf16)s.x, (__bf16)s.y, (__bf16)s.z, (__bf16)s.w };
    *(bf16x4*)(out + i) = o;
}

// ---------------------------------------------------------------------------
// In-place LayerNorm(C=512) + exact GELU on bf16 data, fp32 params.
// ---------------------------------------------------------------------------
__global__ void __launch_bounds__(256)
ln_gelu(bf16* __restrict__ data, const float* __restrict__ w, const float* __restrict__ bp)
{
    __shared__ float red[256];
    const int tid = threadIdx.x;
    const size_t base = (size_t)blockIdx.x * 512;
    float x0 = b2f(data[base + tid]);
    float x1 = b2f(data[base + 256 + tid]);

    red[tid] = x0 + x1;
    __syncthreads();
#pragma unroll
    for (int off = 128; off > 0; off >>= 1) {
        if (tid < off) red[tid] += red[tid + off];
        __syncthreads();
    }
    float mu = red[0] * (1.0f / 512.0f);
    __syncthreads();

    float d0 = x0 - mu, d1 = x1 - mu;
    red[tid] = d0 * d0 + d1 * d1;
    __syncthreads();
#pragma unroll
    for (int off = 128; off > 0; off >>= 1) {
        if (tid < off) red[tid] += red[tid + off];
        __syncthreads();
    }
    float rstd = rsqrtf(red[0] * (1.0f / 512.0f) + 1e-5f);

    float y0 = d0 * rstd * w[tid] + bp[tid];
    float y1 = d1 * rstd * w[256 + tid] + bp[256 + tid];
    y0 = 0.5f * y0 * (1.0f + erff(y0 * 0.70710678118654752f));
    y1 = 0.5f * y1 * (1.0f + erff(y1 * 0.70710678118654752f));
    data[base + tid]       = f2b(y0);
    data[base + 256 + tid] = f2b(y1);
}

// ---------------------------------------------------------------------------
// v + depthwise 3x3 (pad 1) residual, layout (B*hw, 256). bf16 data, fp32 wts.
// ---------------------------------------------------------------------------
__global__ void __launch_bounds__(256)
local_res(const bf16* __restrict__ v, const float* __restrict__ lw,
          const float* __restrict__ lb, bf16* __restrict__ outp,
          int hw_bits, int w1_bits)
{
    const int idx = blockIdx.x * 256 + threadIdx.x;
    const int c   = idx & 255;
    const int pix = (idx >> 8) & ((1 << hw_bits) - 1);
    const int b   = idx >> (8 + hw_bits);
    const int w1  = 1 << w1_bits;
    const int h1  = 1 << (hw_bits - w1_bits);
    const int y = pix >> w1_bits, x = pix & (w1 - 1);

    float acc = b2f(v[idx]) + lb[c];
#pragma unroll
    for (int ky = 0; ky < 3; ++ky) {
        int yy = y + ky - 1;
        if (yy < 0 || yy >= h1) continue;
#pragma unroll
        for (int kx = 0; kx < 3; ++kx) {
            int xx = x + kx - 1;
            if (xx < 0 || xx >= w1) continue;
            acc += lw[c * 9 + ky * 3 + kx] *
                   b2f(v[(((b << hw_bits) + (yy << w1_bits) + xx) << 8) + c]);
        }
    }
    outp[idx] = f2b(acc);
}

// ---------------------------------------------------------------------------
// MFMA attention (unchanged — validated).
// ---------------------------------------------------------------------------
__global__ void __launch_bounds__(256)
attn_mfma(const bf16* __restrict__ qmat, const bf16* __restrict__ kmat,
          const bf16* __restrict__ vmat, bf16* __restrict__ x,
          int Nk, int hoff, int xoff)
{
    __shared__ __bf16 lds_vt[64][40];
    __shared__ __bf16 lds_p[4][16][40];

    const int bid = blockIdx.x;
    const int qt = bid & 15;
    const int h  = (bid >> 4) & 3;
    const int b  = bid >> 6;
    const int tid = threadIdx.x;
    const int w = tid >> 6, lane = tid & 63;
    const int quad = lane >> 4, l16 = lane & 15;

    const int qrow = b * 1024 + qt * 64 + w * 16 + l16;
    const __bf16* qp = (const __bf16*)qmat + (size_t)qrow * 512 + (hoff + h) * 64 + quad * 8;
    const bf16x8 qf0 = *(const bf16x8*)qp;
    const bf16x8 qf1 = *(const bf16x8*)(qp + 32);

    floatx4 acc_o[4];
#pragma unroll
    for (int nt = 0; nt < 4; ++nt) acc_o[nt] = (floatx4){0.f, 0.f, 0.f, 0.f};
    float rs[4] = {0.f, 0.f, 0.f, 0.f};

    const size_t kvbase = (size_t)b * Nk * 256 + (size_t)h * 64;

    for (int j0 = 0; j0 < Nk; j0 += 32) {
        __syncthreads();
        {
            const int jr = tid >> 3;
            const int dc = (tid & 7) * 8;
            bf16x8 vv = *(const bf16x8*)((const __bf16*)vmat + kvbase +
                                         (size_t)(j0 + jr) * 256 + dc);
#pragma unroll
            for (int e = 0; e < 8; ++e)
                lds_vt[dc + e][jr] = vv[e];
        }
        __syncthreads();

#pragma unroll
        for (int jh = 0; jh < 2; ++jh) {
            const __bf16* kp = (const __bf16*)kmat + kvbase +
                               (size_t)(j0 + jh * 16 + l16) * 256 + quad * 8;
            bf16x8 kf0 = *(const bf16x8*)kp;
            bf16x8 kf1 = *(const bf16x8*)(kp + 32);
            floatx4 s = (floatx4){0.f, 0.f, 0.f, 0.f};
            s = __builtin_amdgcn_mfma_f32_16x16x32_bf16(qf0, kf0, s, 0, 0, 0);
            s = __builtin_amdgcn_mfma_f32_16x16x32_bf16(qf1, kf1, s, 0, 0, 0);
#pragma unroll
            for (int r = 0; r < 4; ++r) {
                float p = __expf(s[r] * 0.125f);
                rs[r] += p;
                lds_p[w][quad * 4 + r][jh * 16 + l16] = (__bf16)p;
            }
        }
        bf16x8 pf = *(const bf16x8*)&lds_p[w][l16][quad * 8];
#pragma unroll
        for (int nt = 0; nt < 4; ++nt) {
            bf16x8 vf = *(const bf16x8*)&lds_vt[nt * 16 + l16][quad * 8];
            acc_o[nt] = __builtin_amdgcn_mfma_f32_16x16x32_bf16(pf, vf, acc_o[nt], 0, 0, 0);
        }
    }

#pragma unroll
    for (int r = 0; r < 4; ++r) {
        float v = rs[r];
        v += __shfl_xor(v, 1);
        v += __shfl_xor(v, 2);
        v += __shfl_xor(v, 4);
        v += __shfl_xor(v, 8);
        rs[r] = v;
    }

    const int mg = qt * 64 + w * 16 + quad * 4;
#pragma unroll
    for (int r = 0; r < 4; ++r) {
        const float inv = 1.0f / rs[r];
        __bf16* xr = (__bf16*)x + (size_t)(b * 1024 + mg + r) * 512 + xoff + h * 64;
#pragma unroll
        for (int nt = 0; nt < 4; ++nt)
            xr[nt * 16 + l16] = (__bf16)(acc_o[nt][r] * inv);
    }
}

// ---------------------------------------------------------------------------
extern "C" void kernel_launch(void* const* d_in, const int* in_sizes, int n_in,
                              void* d_out, int out_size, void* d_ws, size_t ws_size,
                              hipStream_t stream)
{
    const float* query   = (const float*)d_in[0];
    const float* key     = (const float*)d_in[1];
    const float* value   = (const float*)d_in[2];
    const float* q_w     = (const float*)d_in[5];
    const float* sr1_w   = (const float*)d_in[6];
    const float* sr1_b   = (const float*)d_in[7];
    const float* norm1_w = (const float*)d_in[8];
    const float* norm1_b = (const float*)d_in[9];
    const float* sr2_w   = (const float*)d_in[10];
    const float* sr2_b   = (const float*)d_in[11];
    const float* norm2_w = (const float*)d_in[12];
    const float* norm2_b = (const float*)d_in[13];
    const float* k1_w    = (const float*)d_in[14];
    /* v1_w = d_in[15] unused: reference (faithfully) uses k1_w for v1 */
    const float* k2_w    = (const float*)d_in[16];
    const float* v2_w    = (const float*)d_in[17];
    const float* lc1_w   = (const float*)d_in[18];
    const float* lc1_b   = (const float*)d_in[19];
    const float* lc2_w   = (const float*)d_in[20];
    const float* lc2_b   = (const float*)d_in[21];
    const float* proj_w  = (const float*)d_in[22];
    const float* proj_b  = (const float*)d_in[23];
    float* out = (float*)d_out;

    // ---- workspace map (MiB offsets), peak ~116 MiB -----------------------
    char* base = (char*)d_ws;
    const size_t MiB = 1024 * 1024;
    __bf16* S     = (__bf16*)(base + 0 * MiB);    // 64 MiB: im2col scratch, then:
    __bf16* qproj = S;                            //   S+0  : 16 MiB (16384x512)
    __bf16* k1    = (__bf16*)(base + 16 * MiB);   //   S+16 :  2 MiB (4096x256)
    __bf16* v1    = (__bf16*)(base + 18 * MiB);   //   S+18 :  2 MiB
    __bf16* k2    = (__bf16*)(base + 20 * MiB);   //   S+20 :  8 MiB (16384x256)
    __bf16* v2    = (__bf16*)(base + 28 * MiB);   //   S+28 :  8 MiB
    __bf16* qbf   = (__bf16*)(base + 36 * MiB);   //   S+36 : 16 MiB (query bf16)
    __bf16* c1k   = (__bf16*)(base + 64 * MiB);   //  4 MiB (4096x512)
    __bf16* c1v   = (__bf16*)(base + 68 * MiB);   //  4 MiB
    __bf16* c2k   = (__bf16*)(base + 72 * MiB);   // 16 MiB (16384x512)
    __bf16* c2v   = (__bf16*)(base + 88 * MiB);   // 16 MiB
    float*  skp   = (float*)(base + 72 * MiB);    // 32 MiB: split-K partials
    __bf16* wq    = (__bf16*)(base + 104 * MiB);  // 0.5 MiB (512x512)
    __bf16* wsr1  = (__bf16*)(base + 104 * MiB + 524288);            // 8 MiB
    __bf16* wsr2  = (__bf16*)(base + 112 * MiB + 524288);            // 2 MiB
    __bf16* wk1   = (__bf16*)(base + 114 * MiB + 524288);            // 0.25
    __bf16* wk2   = (__bf16*)(base + 114 * MiB + 786432);            // 0.25
    __bf16* wv2   = (__bf16*)(base + 115 * MiB);                     // 0.25
    __bf16* wproj = (__bf16*)(base + 115 * MiB + 262144);            // 0.5
    __bf16* v1r   = c1k;   // alias: c1k dead after k1 head-proj
    __bf16* v2r   = c2v;   // alias: c2v dead after v2 head-proj
    __bf16* xbuf  = c2k;   // alias: c2k dead after k2 head-proj

    dim3 blk(256);

    // 1) weights -> bf16 (one launch)
    {
        DcPack p;
        p.e[0] = { q_w,    wq,    512 * 512 };
        p.e[1] = { sr1_w,  wsr1,  512 * 8192 };
        p.e[2] = { sr2_w,  wsr2,  512 * 2048 };
        p.e[3] = { k1_w,   wk1,   256 * 512 };
        p.e[4] = { k2_w,   wk2,   256 * 512 };
        p.e[5] = { v2_w,   wv2,   256 * 512 };
        p.e[6] = { proj_w, wproj, 512 * 512 };
        p.e[7] = { nullptr, nullptr, 0 };
        int maxb = (512 * 8192 / 4 + 255) / 256;
        downcast_all<<<dim3(maxb, 7), blk, 0, stream>>>(p, 7);
    }

    // 2) convs: source-coalesced im2col + MFMA GEMM (split-K for sr1).
    const size_t mn1 = 4096 * 512;
    im2col_sr1<<<dim3(4096), blk, 0, stream>>>(key, S);
    mgemm_sk<64><<<dim3(32, 8, 4), blk, 0, stream>>>(S, wsr1, skp, 512, 8192, 2048, mn1);
    sk_reduce<<<dim3(mn1 / 1024), blk, 0, stream>>>(skp, sr1_b, c1k, mn1, 4, 511);
    im2col_sr1<<<dim3(4096), blk, 0, stream>>>(value, S);
    mgemm_sk<64><<<dim3(32, 8, 4), blk, 0, stream>>>(S, wsr1, skp, 512, 8192, 2048, mn1);
    sk_reduce<<<dim3(mn1 / 1024), blk, 0, stream>>>(skp, sr1_b, c1v, mn1, 4, 511);
    im2col_sr2<<<dim3(1024), blk, 0, stream>>>(key, S);
    mgemm<64, __bf16><<<dim3(128, 8), blk, 0, stream>>>(S, wsr2, sr2_b, c2k, 512, 2048);
    im2col_sr2<<<dim3(1024), blk, 0, stream>>>(value, S);
    mgemm<64, __bf16><<<dim3(128, 8), blk, 0, stream>>>(S, wsr2, sr2_b, c2v, 512, 2048);

    // 3) query -> bf16, then q projection (into S, now free).
    {
        DcPack p;
        p.e[0] = { query, qbf, 16384 * 512 };
        downcast_all<<<dim3(16384 * 512 / 1024, 1), blk, 0, stream>>>(p, 1);
    }
    mgemm<64, __bf16><<<dim3(128, 8), blk, 0, stream>>>(qbf, wq, nullptr, qproj, 512, 512);

    // 4) LayerNorm + GELU (in place)
    ln_gelu<<<dim3(4096),  blk, 0, stream>>>((bf16*)c1k, norm1_w, norm1_b);
    ln_gelu<<<dim3(4096),  blk, 0, stream>>>((bf16*)c1v, norm1_w, norm1_b);
    ln_gelu<<<dim3(16384), blk, 0, stream>>>((bf16*)c2k, norm2_w, norm2_b);
    ln_gelu<<<dim3(16384), blk, 0, stream>>>((bf16*)c2v, norm2_w, norm2_b);

    // 5) head projections (v1 uses k1_w — faithful to source)
    mgemm<64, __bf16><<<dim3(32, 4),  blk, 0, stream>>>(c1k, wk1, nullptr, k1, 256, 512);
    mgemm<64, __bf16><<<dim3(32, 4),  blk, 0, stream>>>(c1v, wk1, nullptr, v1, 256, 512);
    mgemm<64, __bf16><<<dim3(128, 4), blk, 0, stream>>>(c2k, wk2, nullptr, k2, 256, 512);
    mgemm<64, __bf16><<<dim3(128, 4), blk, 0, stream>>>(c2v, wv2, nullptr, v2, 256, 512);

    // 6) depthwise 3x3 residual
    local_res<<<dim3(4096),  blk, 0, stream>>>((bf16*)v1, lc1_w, lc1_b, (bf16*)v1r, 8, 4);
    local_res<<<dim3(16384), blk, 0, stream>>>((bf16*)v2, lc2_w, lc2_b, (bf16*)v2r, 10, 5);

    // 7) MFMA attention
    attn_mfma<<<dim3(1024), blk, 0, stream>>>((bf16*)qproj, (bf16*)k1, (bf16*)v1r,
                                              (bf16*)xbuf, 256, 0, 0);
    attn_mfma<<<dim3(1024), blk, 0, stream>>>((bf16*)qproj, (bf16*)k2, (bf16*)v2r,
                                              (bf16*)xbuf, 1024, 4, 256);

    // 8) out = x @ proj_w^T + proj_b (fp32 out)
    mgemm<64, float><<<dim3(128, 8), blk, 0, stream>>>(xbuf, wproj, proj_b, out, 512, 512);
}

// Round 5
// 953.904 us; speedup vs baseline: 1.3718x; 1.0707x over previous
//
#include <hip/hip_runtime.h>
#include <hip/hip_bf16.h>
#include <math.h>

using bf16 = __hip_bfloat16;

typedef __bf16 bf16x4 __attribute__((ext_vector_type(4)));
typedef __bf16 bf16x8 __attribute__((ext_vector_type(8)));
typedef float  floatx4 __attribute__((ext_vector_type(4)));

__device__ __forceinline__ float b2f(bf16 x) { return __bfloat162float(x); }
__device__ __forceinline__ bf16  f2b(float x) { return __float2bfloat16(x); }

// LDS index swizzle: XOR bits [11:15) into bank bits [2:6). Keeps aligned
// 4-element (8B) groups contiguous (bits [0:2) untouched), breaks the
// x512-element stride conflicts of the im2col gather.
__device__ __forceinline__ int swz(int i) { return i ^ (((i >> 11) & 15) << 2); }

// ---------------------------------------------------------------------------
// Batched fp32 -> bf16 downcast. Up to 8 (src,dst,n) entries in one launch.
// ---------------------------------------------------------------------------
struct DcEnt { const float* s; __bf16* d; int n; };
struct DcPack { DcEnt e[8]; };

__global__ void __launch_bounds__(256)
downcast_all(DcPack p, int n_ent)
{
    const int ei = blockIdx.y;
    if (ei >= n_ent) return;
    const DcEnt ent = p.e[ei];
    const int i4 = (blockIdx.x * 256 + threadIdx.x) * 4;
    if (i4 + 3 >= ent.n) {
        for (int i = i4; i < ent.n; ++i) ent.d[i] = (__bf16)ent.s[i];
        return;
    }
    float4 v = *(const float4*)(ent.s + i4);
    bf16x4 o = { (__bf16)v.x, (__bf16)v.y, (__bf16)v.z, (__bf16)v.w };
    *(bf16x4*)(ent.d + i4) = o;
}

// ---------------------------------------------------------------------------
// Source-coalesced im2col for the 4x4/stride-4 conv (sr1).  (validated R4)
// ---------------------------------------------------------------------------
__global__ void __launch_bounds__(256)
im2col_sr1(const float* __restrict__ src, __bf16* __restrict__ dst)
{
    __shared__ __bf16 lds[8192];
    const int b  = blockIdx.x >> 8;
    const int c2 = blockIdx.x & 255;
    const int tid = threadIdx.x;
    const float* sp = src + ((size_t)(b * 256 + c2) << 13);

#pragma unroll
    for (int i = 0; i < 8; ++i) {
        int idx = (i * 256 + tid) * 4;
        float4 v = *(const float4*)(sp + idx);
        int o = swz(idx);
        lds[o + 0] = (__bf16)v.x; lds[o + 1] = (__bf16)v.y;
        lds[o + 2] = (__bf16)v.z; lds[o + 3] = (__bf16)v.w;
    }
    __syncthreads();

    const int j = tid & 3;
#pragma unroll
    for (int p = 0; p < 4; ++p) {
        int r  = p * 64 + (tid >> 2);
        int oy = r >> 4, ox = r & 15;
        bf16x8 o;
#pragma unroll
        for (int u = 0; u < 8; ++u) {
            int e  = j * 8 + u;
            int cc = e >> 4, ky = (e >> 2) & 3, kx = e & 3;
            int i  = (4 * (ox & 3) + kx) * 512 + cc * 256 +
                     (4 * oy + ky) * 4 + (ox >> 2);
            o[u] = lds[swz(i)];
        }
        *(bf16x8*)(dst + ((size_t)(b * 256 + r) << 13) + c2 * 32 + j * 8) = o;
    }
}

// ---------------------------------------------------------------------------
// Source-coalesced im2col for the 2x2/stride-2 conv (sr2).  (validated R4)
// ---------------------------------------------------------------------------
__global__ void __launch_bounds__(256)
im2col_sr2(const float* __restrict__ src, __bf16* __restrict__ dst)
{
    __shared__ __bf16 lds[32768];
    const int b  = blockIdx.x >> 6;
    const int cg = blockIdx.x & 63;
    const int tid = threadIdx.x;
    const float* sp = src + ((size_t)(b * 256 + cg * 4) << 13);

#pragma unroll
    for (int i = 0; i < 32; ++i) {
        int idx = (i * 256 + tid) * 4;
        float4 v = *(const float4*)(sp + idx);
        int o = swz(idx);
        lds[o + 0] = (__bf16)v.x; lds[o + 1] = (__bf16)v.y;
        lds[o + 2] = (__bf16)v.z; lds[o + 3] = (__bf16)v.w;
    }
    __syncthreads();

    const int j = tid & 3;
#pragma unroll
    for (int p = 0; p < 16; ++p) {
        int r  = p * 64 + (tid >> 2);
        int oy = r >> 5, ox = r & 31;
        bf16x8 o;
#pragma unroll
        for (int u = 0; u < 8; ++u) {
            int cc = (u >> 2) & 1, ky = (u >> 1) & 1, kx = u & 1;
            int i  = j * 8192 + (2 * (ox & 7) + kx) * 512 + cc * 256 +
                     (2 * oy + ky) * 4 + (ox >> 3);
            o[u] = lds[swz(i)];
        }
        *(bf16x8*)(dst + ((size_t)(b * 1024 + r) << 11) + cg * 32 + j * 8) = o;
    }
}

// ---------------------------------------------------------------------------
// MFMA GEMM: C[M,N] = A[M,K] @ B[N,K]^T (+bias).  (validated)
// ---------------------------------------------------------------------------
template <int BN, typename OutT>
__global__ void __launch_bounds__(256)
mgemm(const __bf16* __restrict__ A, const __bf16* __restrict__ B,
      const float* __restrict__ bias, OutT* __restrict__ C,
      int N, int K)
{
    constexpr int BM = 128, BK = 64;
    constexpr int PK = BK + 8;
    constexpr int NI = BN / 32;
    __shared__ __bf16 Asl[BM * PK];
    __shared__ __bf16 Bsl[BN * PK];

    const int tid  = threadIdx.x;
    const int w    = tid >> 6, lane = tid & 63;
    const int quad = lane >> 4, l16 = lane & 15;
    const int wm   = (w >> 1) * 64, wn = (w & 1) * (BN / 2);
    const int m0   = blockIdx.x * BM, n0 = blockIdx.y * BN;

    floatx4 acc[4][NI];
#pragma unroll
    for (int mi = 0; mi < 4; ++mi)
#pragma unroll
        for (int ni = 0; ni < NI; ++ni)
            acc[mi][ni] = (floatx4){0.f, 0.f, 0.f, 0.f};

    for (int k0 = 0; k0 < K; k0 += BK) {
#pragma unroll
        for (int i = 0; i < (BM * BK / 8) / 256; ++i) {
            int idx = (i * 256 + tid) * 8;
            int m = idx >> 6, kk = idx & 63;
            *(bf16x8*)&Asl[m * PK + kk] =
                *(const bf16x8*)&A[(size_t)(m0 + m) * K + k0 + kk];
        }
#pragma unroll
        for (int i = 0; i < (BN * BK / 8) / 256; ++i) {
            int idx = (i * 256 + tid) * 8;
            int n = idx >> 6, kk = idx & 63;
            *(bf16x8*)&Bsl[n * PK + kk] =
                *(const bf16x8*)&B[(size_t)(n0 + n) * K + k0 + kk];
        }
        __syncthreads();
#pragma unroll
        for (int ks = 0; ks < 2; ++ks) {
            bf16x8 af[4], bf[NI];
#pragma unroll
            for (int mi = 0; mi < 4; ++mi)
                af[mi] = *(const bf16x8*)&Asl[(wm + mi * 16 + l16) * PK + ks * 32 + quad * 8];
#pragma unroll
            for (int ni = 0; ni < NI; ++ni)
                bf[ni] = *(const bf16x8*)&Bsl[(wn + ni * 16 + l16) * PK + ks * 32 + quad * 8];
#pragma unroll
            for (int mi = 0; mi < 4; ++mi)
#pragma unroll
                for (int ni = 0; ni < NI; ++ni)
                    acc[mi][ni] = __builtin_amdgcn_mfma_f32_16x16x32_bf16(
                        af[mi], bf[ni], acc[mi][ni], 0, 0, 0);
        }
        __syncthreads();
    }

#pragma unroll
    for (int mi = 0; mi < 4; ++mi)
#pragma unroll
        for (int r = 0; r < 4; ++r) {
            int row = m0 + wm + mi * 16 + quad * 4 + r;
#pragma unroll
            for (int ni = 0; ni < NI; ++ni) {
                int col = n0 + wn + ni * 16 + l16;
                float v = acc[mi][ni][r];
                if (bias) v += bias[col];
                C[(size_t)row * N + col] = (OutT)v;
            }
        }
}

// ---------------------------------------------------------------------------
// Split-K MFMA GEMM (fp32 partials, no bias).  (validated)
// ---------------------------------------------------------------------------
template <int BN>
__global__ void __launch_bounds__(256)
mgemm_sk(const __bf16* __restrict__ A, const __bf16* __restrict__ B,
         float* __restrict__ P, int N, int K, int KC, size_t mn)
{
    constexpr int BM = 128, BK = 64;
    constexpr int PK = BK + 8;
    constexpr int NI = BN / 32;
    __shared__ __bf16 Asl[BM * PK];
    __shared__ __bf16 Bsl[BN * PK];

    const int tid  = threadIdx.x;
    const int w    = tid >> 6, lane = tid & 63;
    const int quad = lane >> 4, l16 = lane & 15;
    const int wm   = (w >> 1) * 64, wn = (w & 1) * (BN / 2);
    const int m0   = blockIdx.x * BM, n0 = blockIdx.y * BN;
    const int kbeg = blockIdx.z * KC;

    floatx4 acc[4][NI];
#pragma unroll
    for (int mi = 0; mi < 4; ++mi)
#pragma unroll
        for (int ni = 0; ni < NI; ++ni)
            acc[mi][ni] = (floatx4){0.f, 0.f, 0.f, 0.f};

    for (int k0 = kbeg; k0 < kbeg + KC; k0 += BK) {
#pragma unroll
        for (int i = 0; i < (BM * BK / 8) / 256; ++i) {
            int idx = (i * 256 + tid) * 8;
            int m = idx >> 6, kk = idx & 63;
            *(bf16x8*)&Asl[m * PK + kk] =
                *(const bf16x8*)&A[(size_t)(m0 + m) * K + k0 + kk];
        }
#pragma unroll
        for (int i = 0; i < (BN * BK / 8) / 256; ++i) {
            int idx = (i * 256 + tid) * 8;
            int n = idx >> 6, kk = idx & 63;
            *(bf16x8*)&Bsl[n * PK + kk] =
                *(const bf16x8*)&B[(size_t)(n0 + n) * K + k0 + kk];
        }
        __syncthreads();
#pragma unroll
        for (int ks = 0; ks < 2; ++ks) {
            bf16x8 af[4], bf[NI];
#pragma unroll
            for (int mi = 0; mi < 4; ++mi)
                af[mi] = *(const bf16x8*)&Asl[(wm + mi * 16 + l16) * PK + ks * 32 + quad * 8];
#pragma unroll
            for (int ni = 0; ni < NI; ++ni)
                bf[ni] = *(const bf16x8*)&Bsl[(wn + ni * 16 + l16) * PK + ks * 32 + quad * 8];
#pragma unroll
            for (int mi = 0; mi < 4; ++mi)
#pragma unroll
                for (int ni = 0; ni < NI; ++ni)
                    acc[mi][ni] = __builtin_amdgcn_mfma_f32_16x16x32_bf16(
                        af[mi], bf[ni], acc[mi][ni], 0, 0, 0);
        }
        __syncthreads();
    }

    float* Pz = P + (size_t)blockIdx.z * mn;
#pragma unroll
    for (int mi = 0; mi < 4; ++mi)
#pragma unroll
        for (int r = 0; r < 4; ++r) {
            int row = m0 + wm + mi * 16 + quad * 4 + r;
#pragma unroll
            for (int ni = 0; ni < NI; ++ni) {
                int col = n0 + wn + ni * 16 + l16;
                Pz[(size_t)row * N + col] = acc[mi][ni][r];
            }
        }
}

// ---------------------------------------------------------------------------
// Split-K reduce: out[i] = bf16( sum_z P[z*mn + i] + bias[i & nmask] ).
// ---------------------------------------------------------------------------
__global__ void __launch_bounds__(256)
sk_reduce(const float* __restrict__ P, const float* __restrict__ bias,
          __bf16* __restrict__ out, size_t mn, int nsplit, int nmask)
{
    const size_t i = ((size_t)blockIdx.x * 256 + threadIdx.x) * 4;
    if (i >= mn) return;
    float4 s = *(const float4*)(P + i);
    for (int z = 1; z < nsplit; ++z) {
        float4 t = *(const float4*)(P + (size_t)z * mn + i);
        s.x += t.x; s.y += t.y; s.z += t.z; s.w += t.w;
    }
    if (bias) {
        const int c = (int)(i & (size_t)nmask);
        s.x += bias[c]; s.y += bias[c + 1]; s.z += bias[c + 2]; s.w += bias[c + 3];
    }
    bf16x4 o = { (__bf16)s.x, (__bf16)s.y, (__bf16)s.z, (__bf16)s.w };
    *(bf16x4*)(out + i) = o;
}

// ---------------------------------------------------------------------------
// In-place LayerNorm(C=512) + exact GELU on bf16 data, fp32 params.
// ---------------------------------------------------------------------------
__global__ void __launch_bounds__(256)
ln_gelu(bf16* __restrict__ data, const float* __restrict__ w, const float* __restrict__ bp)
{
    __shared__ float red[256];
    const int tid = threadIdx.x;
    const size_t base = (size_t)blockIdx.x * 512;
    float x0 = b2f(data[base + tid]);
    float x1 = b2f(data[base + 256 + tid]);

    red[tid] = x0 + x1;
    __syncthreads();
#pragma unroll
    for (int off = 128; off > 0; off >>= 1) {
        if (tid < off) red[tid] += red[tid + off];
        __syncthreads();
    }
    float mu = red[0] * (1.0f / 512.0f);
    __syncthreads();

    float d0 = x0 - mu, d1 = x1 - mu;
    red[tid] = d0 * d0 + d1 * d1;
    __syncthreads();
#pragma unroll
    for (int off = 128; off > 0; off >>= 1) {
        if (tid < off) red[tid] += red[tid + off];
        __syncthreads();
    }
    float rstd = rsqrtf(red[0] * (1.0f / 512.0f) + 1e-5f);

    float y0 = d0 * rstd * w[tid] + bp[tid];
    float y1 = d1 * rstd * w[256 + tid] + bp[256 + tid];
    y0 = 0.5f * y0 * (1.0f + erff(y0 * 0.70710678118654752f));
    y1 = 0.5f * y1 * (1.0f + erff(y1 * 0.70710678118654752f));
    data[base + tid]       = f2b(y0);
    data[base + 256 + tid] = f2b(y1);
}

// ---------------------------------------------------------------------------
// v + depthwise 3x3 (pad 1) residual, layout (B*hw, 256). bf16 data, fp32 wts.
// ---------------------------------------------------------------------------
__global__ void __launch_bounds__(256)
local_res(const bf16* __restrict__ v, const float* __restrict__ lw,
          const float* __restrict__ lb, bf16* __restrict__ outp,
          int hw_bits, int w1_bits)
{
    const int idx = blockIdx.x * 256 + threadIdx.x;
    const int c   = idx & 255;
    const int pix = (idx >> 8) & ((1 << hw_bits) - 1);
    const int b   = idx >> (8 + hw_bits);
    const int w1  = 1 << w1_bits;
    const int h1  = 1 << (hw_bits - w1_bits);
    const int y = pix >> w1_bits, x = pix & (w1 - 1);

    float acc = b2f(v[idx]) + lb[c];
#pragma unroll
    for (int ky = 0; ky < 3; ++ky) {
        int yy = y + ky - 1;
        if (yy < 0 || yy >= h1) continue;
#pragma unroll
        for (int kx = 0; kx < 3; ++kx) {
            int xx = x + kx - 1;
            if (xx < 0 || xx >= w1) continue;
            acc += lw[c * 9 + ky * 3 + kx] *
                   b2f(v[(((b << hw_bits) + (yy << w1_bits) + xx) << 8) + c]);
        }
    }
    outp[idx] = f2b(acc);
}

// ---------------------------------------------------------------------------
// V transpose: in (b*Nk + j, 256) -> out (b*256 + c)*Nk + j.  64x64 LDS tile,
// chunk-XOR swizzle (ch ^= (j>>3)&7) keeps both passes <=2-way on banks.
// grid: (Nk/64, 4, B), 256 threads.
// ---------------------------------------------------------------------------
__global__ void __launch_bounds__(256)
vtrans(const __bf16* __restrict__ in, __bf16* __restrict__ out, int Nk)
{
    __shared__ __bf16 t[64][72];
    const int jt = blockIdx.x, cg = blockIdx.y, b = blockIdx.z;
    const int tid = threadIdx.x;
    const int chunk = tid & 7;

#pragma unroll
    for (int i = 0; i < 2; ++i) {
        int jr = i * 32 + (tid >> 3);
        bf16x8 v = *(const bf16x8*)(in + ((size_t)(b * Nk + jt * 64 + jr) << 8)
                                       + cg * 64 + chunk * 8);
        int ch = chunk ^ ((jr >> 3) & 7);
        *(bf16x8*)&t[jr][ch * 8] = v;
    }
    __syncthreads();

#pragma unroll
    for (int i = 0; i < 2; ++i) {
        int cr = i * 32 + (tid >> 3);
        int jc = tid & 7;
        bf16x8 o;
#pragma unroll
        for (int u = 0; u < 8; ++u) {
            int j  = jc * 8 + u;
            int ch = (cr >> 3) ^ ((j >> 3) & 7);
            o[u] = t[j][ch * 8 + (cr & 7)];
        }
        *(bf16x8*)(out + (size_t)(b * 256 + cg * 64 + cr) * Nk + jt * 64 + jc * 8) = o;
    }
}

// ---------------------------------------------------------------------------
// MFMA attention v2. V is PRE-TRANSPOSED (vtmat: (b*256 + c)*Nk + j), so both
// K and V^T tiles stage with one coalesced b128 write/thread (no scalar
// transpose: old version had a provable 16-way bank conflict on lds_vt
// writes = 1.73e7 conflict cycles = ~28% of kernel time). K staged in LDS
// once per block (was loaded 4x redundantly per wave). Next tile register-
// prefetched during compute to hide global latency across the barriers.
// Numerics identical to validated v1 (same values, same MFMA order).
// ---------------------------------------------------------------------------
__global__ void __launch_bounds__(256)
attn_mfma(const bf16* __restrict__ qmat, const bf16* __restrict__ kmat,
          const bf16* __restrict__ vtmat, bf16* __restrict__ x,
          int Nk, int hoff, int xoff)
{
    __shared__ __bf16 lds_k[32][72];   // K tile: 32 j x 64 d (144B rows: 2-way)
    __shared__ __bf16 lds_vt[64][40];  // V^T tile: 64 d x 32 j (80B rows: 2-way)
    __shared__ __bf16 lds_p[4][16][40];

    const int bid = blockIdx.x;
    const int qt = bid & 15;
    const int h  = (bid >> 4) & 3;
    const int b  = bid >> 6;
    const int tid = threadIdx.x;
    const int w = tid >> 6, lane = tid & 63;
    const int quad = lane >> 4, l16 = lane & 15;

    const int qrow = b * 1024 + qt * 64 + w * 16 + l16;
    const __bf16* qp = (const __bf16*)qmat + (size_t)qrow * 512 + (hoff + h) * 64 + quad * 8;
    const bf16x8 qf0 = *(const bf16x8*)qp;
    const bf16x8 qf1 = *(const bf16x8*)(qp + 32);

    // staging source addresses (this thread's 16B chunk of each tile)
    const __bf16* ksrc = (const __bf16*)kmat + ((size_t)b * Nk << 8)
                         + (size_t)(tid >> 3) * 256 + h * 64 + (tid & 7) * 8;
    const __bf16* vsrc = (const __bf16*)vtmat
                         + (size_t)(b * 256 + h * 64 + (tid >> 2)) * Nk + (tid & 3) * 8;

    bf16x8 kreg = *(const bf16x8*)ksrc;          // prefetch tile 0
    bf16x8 vreg = *(const bf16x8*)vsrc;

    floatx4 acc_o[4];
#pragma unroll
    for (int nt = 0; nt < 4; ++nt) acc_o[nt] = (floatx4){0.f, 0.f, 0.f, 0.f};
    float rs[4] = {0.f, 0.f, 0.f, 0.f};

    for (int j0 = 0; j0 < Nk; j0 += 32) {
        __syncthreads();                          // prev iter done reading LDS
        *(bf16x8*)&lds_k[tid >> 3][(tid & 7) * 8] = kreg;
        *(bf16x8*)&lds_vt[tid >> 2][(tid & 3) * 8] = vreg;
        __syncthreads();                          // staging visible
        if (j0 + 32 < Nk) {                       // prefetch next tile
            kreg = *(const bf16x8*)(ksrc + ((size_t)(j0 + 32) << 8));
            vreg = *(const bf16x8*)(vsrc + j0 + 32);
        }

#pragma unroll
        for (int jh = 0; jh < 2; ++jh) {
            const __bf16* kp = &lds_k[jh * 16 + l16][quad * 8];
            bf16x8 kf0 = *(const bf16x8*)kp;
            bf16x8 kf1 = *(const bf16x8*)(kp + 32);
            floatx4 s = (floatx4){0.f, 0.f, 0.f, 0.f};
            s = __builtin_amdgcn_mfma_f32_16x16x32_bf16(qf0, kf0, s, 0, 0, 0);
            s = __builtin_amdgcn_mfma_f32_16x16x32_bf16(qf1, kf1, s, 0, 0, 0);
#pragma unroll
            for (int r = 0; r < 4; ++r) {
                float p = __expf(s[r] * 0.125f);
                rs[r] += p;
                lds_p[w][quad * 4 + r][jh * 16 + l16] = (__bf16)p;
            }
        }
        bf16x8 pf = *(const bf16x8*)&lds_p[w][l16][quad * 8];
#pragma unroll
        for (int nt = 0; nt < 4; ++nt) {
            bf16x8 vf = *(const bf16x8*)&lds_vt[nt * 16 + l16][quad * 8];
            acc_o[nt] = __builtin_amdgcn_mfma_f32_16x16x32_bf16(pf, vf, acc_o[nt], 0, 0, 0);
        }
    }

#pragma unroll
    for (int r = 0; r < 4; ++r) {
        float v = rs[r];
        v += __shfl_xor(v, 1);
        v += __shfl_xor(v, 2);
        v += __shfl_xor(v, 4);
        v += __shfl_xor(v, 8);
        rs[r] = v;
    }

    const int mg = qt * 64 + w * 16 + quad * 4;
#pragma unroll
    for (int r = 0; r < 4; ++r) {
        const float inv = 1.0f / rs[r];
        __bf16* xr = (__bf16*)x + (size_t)(b * 1024 + mg + r) * 512 + xoff + h * 64;
#pragma unroll
        for (int nt = 0; nt < 4; ++nt)
            xr[nt * 16 + l16] = (__bf16)(acc_o[nt][r] * inv);
    }
}

// ---------------------------------------------------------------------------
extern "C" void kernel_launch(void* const* d_in, const int* in_sizes, int n_in,
                              void* d_out, int out_size, void* d_ws, size_t ws_size,
                              hipStream_t stream)
{
    const float* query   = (const float*)d_in[0];
    const float* key     = (const float*)d_in[1];
    const float* value   = (const float*)d_in[2];
    const float* q_w     = (const float*)d_in[5];
    const float* sr1_w   = (const float*)d_in[6];
    const float* sr1_b   = (const float*)d_in[7];
    const float* norm1_w = (const float*)d_in[8];
    const float* norm1_b = (const float*)d_in[9];
    const float* sr2_w   = (const float*)d_in[10];
    const float* sr2_b   = (const float*)d_in[11];
    const float* norm2_w = (const float*)d_in[12];
    const float* norm2_b = (const float*)d_in[13];
    const float* k1_w    = (const float*)d_in[14];
    /* v1_w = d_in[15] unused: reference (faithfully) uses k1_w for v1 */
    const float* k2_w    = (const float*)d_in[16];
    const float* v2_w    = (const float*)d_in[17];
    const float* lc1_w   = (const float*)d_in[18];
    const float* lc1_b   = (const float*)d_in[19];
    const float* lc2_w   = (const float*)d_in[20];
    const float* lc2_b   = (const float*)d_in[21];
    const float* proj_w  = (const float*)d_in[22];
    const float* proj_b  = (const float*)d_in[23];
    float* out = (float*)d_out;

    // ---- workspace map (MiB offsets), peak ~116 MiB -----------------------
    char* base = (char*)d_ws;
    const size_t MiB = 1024 * 1024;
    __bf16* S     = (__bf16*)(base + 0 * MiB);    // 64 MiB: im2col scratch, then:
    __bf16* qproj = S;                            //   S+0  : 16 MiB (16384x512)
    __bf16* k1    = (__bf16*)(base + 16 * MiB);   //   S+16 :  2 MiB (4096x256)
    __bf16* v1    = (__bf16*)(base + 18 * MiB);   //   S+18 :  2 MiB
    __bf16* k2    = (__bf16*)(base + 20 * MiB);   //   S+20 :  8 MiB (16384x256)
    __bf16* v2    = (__bf16*)(base + 28 * MiB);   //   S+28 :  8 MiB
    __bf16* qbf   = (__bf16*)(base + 36 * MiB);   //   S+36 : 16 MiB (query bf16;
                                                  //   dead after q-proj GEMM)
    __bf16* vt2   = (__bf16*)(base + 36 * MiB);   //   reuse: 8 MiB V2^T
    __bf16* vt1   = (__bf16*)(base + 44 * MiB);   //   reuse: 2 MiB V1^T
    __bf16* c1k   = (__bf16*)(base + 64 * MiB);   //  4 MiB (4096x512)
    __bf16* c1v   = (__bf16*)(base + 68 * MiB);   //  4 MiB
    __bf16* c2k   = (__bf16*)(base + 72 * MiB);   // 16 MiB (16384x512)
    __bf16* c2v   = (__bf16*)(base + 88 * MiB);   // 16 MiB
    float*  skp   = (float*)(base + 72 * MiB);    // 32 MiB: split-K partials
    __bf16* wq    = (__bf16*)(base + 104 * MiB);  // 0.5 MiB (512x512)
    __bf16* wsr1  = (__bf16*)(base + 104 * MiB + 524288);            // 8 MiB
    __bf16* wsr2  = (__bf16*)(base + 112 * MiB + 524288);            // 2 MiB
    __bf16* wk1   = (__bf16*)(base + 114 * MiB + 524288);            // 0.25
    __bf16* wk2   = (__bf16*)(base + 114 * MiB + 786432);            // 0.25
    __bf16* wv2   = (__bf16*)(base + 115 * MiB);                     // 0.25
    __bf16* wproj = (__bf16*)(base + 115 * MiB + 262144);            // 0.5
    __bf16* v1r   = c1k;   // alias: c1k dead after k1 head-proj
    __bf16* v2r   = c2v;   // alias: c2v dead after v2 head-proj
    __bf16* xbuf  = c2k;   // alias: c2k dead after k2 head-proj

    dim3 blk(256);

    // 1) weights -> bf16 (one launch)
    {
        DcPack p;
        p.e[0] = { q_w,    wq,    512 * 512 };
        p.e[1] = { sr1_w,  wsr1,  512 * 8192 };
        p.e[2] = { sr2_w,  wsr2,  512 * 2048 };
        p.e[3] = { k1_w,   wk1,   256 * 512 };
        p.e[4] = { k2_w,   wk2,   256 * 512 };
        p.e[5] = { v2_w,   wv2,   256 * 512 };
        p.e[6] = { proj_w, wproj, 512 * 512 };
        p.e[7] = { nullptr, nullptr, 0 };
        int maxb = (512 * 8192 / 4 + 255) / 256;
        downcast_all<<<dim3(maxb, 7), blk, 0, stream>>>(p, 7);
    }

    // 2) convs: source-coalesced im2col + MFMA GEMM (split-K for sr1).
    const size_t mn1 = 4096 * 512;
    im2col_sr1<<<dim3(4096), blk, 0, stream>>>(key, S);
    mgemm_sk<64><<<dim3(32, 8, 4), blk, 0, stream>>>(S, wsr1, skp, 512, 8192, 2048, mn1);
    sk_reduce<<<dim3(mn1 / 1024), blk, 0, stream>>>(skp, sr1_b, c1k, mn1, 4, 511);
    im2col_sr1<<<dim3(4096), blk, 0, stream>>>(value, S);
    mgemm_sk<64><<<dim3(32, 8, 4), blk, 0, stream>>>(S, wsr1, skp, 512, 8192, 2048, mn1);
    sk_reduce<<<dim3(mn1 / 1024), blk, 0, stream>>>(skp, sr1_b, c1v, mn1, 4, 511);
    im2col_sr2<<<dim3(1024), blk, 0, stream>>>(key, S);
    mgemm<64, __bf16><<<dim3(128, 8), blk, 0, stream>>>(S, wsr2, sr2_b, c2k, 512, 2048);
    im2col_sr2<<<dim3(1024), blk, 0, stream>>>(value, S);
    mgemm<64, __bf16><<<dim3(128, 8), blk, 0, stream>>>(S, wsr2, sr2_b, c2v, 512, 2048);

    // 3) query -> bf16, then q projection (into S, now free).
    {
        DcPack p;
        p.e[0] = { query, qbf, 16384 * 512 };
        downcast_all<<<dim3(16384 * 512 / 1024, 1), blk, 0, stream>>>(p, 1);
    }
    mgemm<64, __bf16><<<dim3(128, 8), blk, 0, stream>>>(qbf, wq, nullptr, qproj, 512, 512);

    // 4) LayerNorm + GELU (in place)
    ln_gelu<<<dim3(4096),  blk, 0, stream>>>((bf16*)c1k, norm1_w, norm1_b);
    ln_gelu<<<dim3(4096),  blk, 0, stream>>>((bf16*)c1v, norm1_w, norm1_b);
    ln_gelu<<<dim3(16384), blk, 0, stream>>>((bf16*)c2k, norm2_w, norm2_b);
    ln_gelu<<<dim3(16384), blk, 0, stream>>>((bf16*)c2v, norm2_w, norm2_b);

    // 5) head projections (v1 uses k1_w — faithful to source)
    mgemm<64, __bf16><<<dim3(32, 4),  blk, 0, stream>>>(c1k, wk1, nullptr, k1, 256, 512);
    mgemm<64, __bf16><<<dim3(32, 4),  blk, 0, stream>>>(c1v, wk1, nullptr, v1, 256, 512);
    mgemm<64, __bf16><<<dim3(128, 4), blk, 0, stream>>>(c2k, wk2, nullptr, k2, 256, 512);
    mgemm<64, __bf16><<<dim3(128, 4), blk, 0, stream>>>(c2v, wv2, nullptr, v2, 256, 512);

    // 6) depthwise 3x3 residual, then V -> V^T for the attention PV step
    local_res<<<dim3(4096),  blk, 0, stream>>>((bf16*)v1, lc1_w, lc1_b, (bf16*)v1r, 8, 4);
    local_res<<<dim3(16384), blk, 0, stream>>>((bf16*)v2, lc2_w, lc2_b, (bf16*)v2r, 10, 5);
    vtrans<<<dim3(4, 4, 16),  blk, 0, stream>>>(v1r, vt1, 256);
    vtrans<<<dim3(16, 4, 16), blk, 0, stream>>>(v2r, vt2, 1024);

    // 7) MFMA attention (K + pre-transposed V^T, LDS-staged, prefetched)
    attn_mfma<<<dim3(1024), blk, 0, stream>>>((bf16*)qproj, (bf16*)k1, (bf16*)vt1,
                                              (bf16*)xbuf, 256, 0, 0);
    attn_mfma<<<dim3(1024), blk, 0, stream>>>((bf16*)qproj, (bf16*)k2, (bf16*)vt2,
                                              (bf16*)xbuf, 1024, 4, 256);

    // 8) out = x @ proj_w^T + proj_b (fp32 out)
    mgemm<64, float><<<dim3(128, 8), blk, 0, stream>>>(xbuf, wproj, proj_b, out, 512, 512);
}

// Round 6
// 951.950 us; speedup vs baseline: 1.3746x; 1.0021x over previous
//
#include <hip/hip_runtime.h>
#include <hip/hip_bf16.h>
#include <math.h>

using bf16 = __hip_bfloat16;

typedef __bf16 bf16x4 __attribute__((ext_vector_type(4)));
typedef __bf16 bf16x8 __attribute__((ext_vector_type(8)));
typedef float  floatx4 __attribute__((ext_vector_type(4)));

__device__ __forceinline__ float b2f(bf16 x) { return __bfloat162float(x); }
__device__ __forceinline__ bf16  f2b(float x) { return __float2bfloat16(x); }

// LDS index swizzle: XOR bits [11:15) into bank bits [2:6). Keeps aligned
// 4-element (8B) groups contiguous (bits [0:2) untouched), breaks the
// x512-element stride conflicts of the im2col gather.
__device__ __forceinline__ int swz(int i) { return i ^ (((i >> 11) & 15) << 2); }

// ---------------------------------------------------------------------------
// Batched fp32 -> bf16 downcast. Up to 8 (src,dst,n) entries in one launch.
// ---------------------------------------------------------------------------
struct DcEnt { const float* s; __bf16* d; int n; };
struct DcPack { DcEnt e[8]; };

__global__ void __launch_bounds__(256)
downcast_all(DcPack p, int n_ent)
{
    const int ei = blockIdx.y;
    if (ei >= n_ent) return;
    const DcEnt ent = p.e[ei];
    const int i4 = (blockIdx.x * 256 + threadIdx.x) * 4;
    if (i4 + 3 >= ent.n) {
        for (int i = i4; i < ent.n; ++i) ent.d[i] = (__bf16)ent.s[i];
        return;
    }
    float4 v = *(const float4*)(ent.s + i4);
    bf16x4 o = { (__bf16)v.x, (__bf16)v.y, (__bf16)v.z, (__bf16)v.w };
    *(bf16x4*)(ent.d + i4) = o;
}

// ---------------------------------------------------------------------------
// Source-coalesced im2col for the 4x4/stride-4 conv (sr1).
// R5 PMC showed VGPR_Count=24: compiler serialized the 8 staging loads
// (8 float4 results need 32 VGPRs) -> exposed HBM latency, 79 us with all
// pipes <21%. Fix: explicit 8-deep load batch into named registers, then
// convert + ONE ds_write_b64 per float4 (was 4x scalar b16 = the 3.1M
// bank-conflict source).
// ---------------------------------------------------------------------------
__global__ void __launch_bounds__(256)
im2col_sr1(const float* __restrict__ src, __bf16* __restrict__ dst)
{
    __shared__ __bf16 lds[8192];
    const int b  = blockIdx.x >> 8;
    const int c2 = blockIdx.x & 255;
    const int tid = threadIdx.x;
    const float* sp = src + ((size_t)(b * 256 + c2) << 13);

    float4 r[8];
#pragma unroll
    for (int i = 0; i < 8; ++i)
        r[i] = *(const float4*)(sp + (i * 256 + tid) * 4);
#pragma unroll
    for (int i = 0; i < 8; ++i) {
        int idx = (i * 256 + tid) * 4;
        bf16x4 o4 = { (__bf16)r[i].x, (__bf16)r[i].y,
                      (__bf16)r[i].z, (__bf16)r[i].w };
        *(bf16x4*)&lds[swz(idx)] = o4;
    }
    __syncthreads();

    const int j = tid & 3;
#pragma unroll
    for (int p = 0; p < 4; ++p) {
        int r2 = p * 64 + (tid >> 2);
        int oy = r2 >> 4, ox = r2 & 15;
        bf16x8 o;
#pragma unroll
        for (int u = 0; u < 8; ++u) {
            int e  = j * 8 + u;
            int cc = e >> 4, ky = (e >> 2) & 3, kx = e & 3;
            int i  = (4 * (ox & 3) + kx) * 512 + cc * 256 +
                     (4 * oy + ky) * 4 + (ox >> 2);
            o[u] = lds[swz(i)];
        }
        *(bf16x8*)(dst + ((size_t)(b * 256 + r2) << 13) + c2 * 32 + j * 8) = o;
    }
}

// ---------------------------------------------------------------------------
// Source-coalesced im2col for the 2x2/stride-2 conv (sr2). K=2048.
// Same fix as sr1: 16-deep explicit load batches (2 rounds; 64 VGPRs data,
// stays under the 128-VGPR occupancy step) + b64 LDS writes.
// ---------------------------------------------------------------------------
__global__ void __launch_bounds__(256)
im2col_sr2(const float* __restrict__ src, __bf16* __restrict__ dst)
{
    __shared__ __bf16 lds[32768];
    const int b  = blockIdx.x >> 6;
    const int cg = blockIdx.x & 63;
    const int tid = threadIdx.x;
    const float* sp = src + ((size_t)(b * 256 + cg * 4) << 13);

#pragma unroll
    for (int half = 0; half < 2; ++half) {
        float4 r[16];
#pragma unroll
        for (int i = 0; i < 16; ++i)
            r[i] = *(const float4*)(sp + ((half * 16 + i) * 256 + tid) * 4);
#pragma unroll
        for (int i = 0; i < 16; ++i) {
            int idx = ((half * 16 + i) * 256 + tid) * 4;
            bf16x4 o4 = { (__bf16)r[i].x, (__bf16)r[i].y,
                          (__bf16)r[i].z, (__bf16)r[i].w };
            *(bf16x4*)&lds[swz(idx)] = o4;
        }
    }
    __syncthreads();

    const int j = tid & 3;
#pragma unroll
    for (int p = 0; p < 16; ++p) {
        int r2 = p * 64 + (tid >> 2);
        int oy = r2 >> 5, ox = r2 & 31;
        bf16x8 o;
#pragma unroll
        for (int u = 0; u < 8; ++u) {
            int cc = (u >> 2) & 1, ky = (u >> 1) & 1, kx = u & 1;
            int i  = j * 8192 + (2 * (ox & 7) + kx) * 512 + cc * 256 +
                     (2 * oy + ky) * 4 + (ox >> 3);
            o[u] = lds[swz(i)];
        }
        *(bf16x8*)(dst + ((size_t)(b * 1024 + r2) << 11) + cg * 32 + j * 8) = o;
    }
}

// ---------------------------------------------------------------------------
// MFMA GEMM: C[M,N] = A[M,K] @ B[N,K]^T (+bias).  (validated)
// ---------------------------------------------------------------------------
template <int BN, typename OutT>
__global__ void __launch_bounds__(256)
mgemm(const __bf16* __restrict__ A, const __bf16* __restrict__ B,
      const float* __restrict__ bias, OutT* __restrict__ C,
      int N, int K)
{
    constexpr int BM = 128, BK = 64;
    constexpr int PK = BK + 8;
    constexpr int NI = BN / 32;
    __shared__ __bf16 Asl[BM * PK];
    __shared__ __bf16 Bsl[BN * PK];

    const int tid  = threadIdx.x;
    const int w    = tid >> 6, lane = tid & 63;
    const int quad = lane >> 4, l16 = lane & 15;
    const int wm   = (w >> 1) * 64, wn = (w & 1) * (BN / 2);
    const int m0   = blockIdx.x * BM, n0 = blockIdx.y * BN;

    floatx4 acc[4][NI];
#pragma unroll
    for (int mi = 0; mi < 4; ++mi)
#pragma unroll
        for (int ni = 0; ni < NI; ++ni)
            acc[mi][ni] = (floatx4){0.f, 0.f, 0.f, 0.f};

    for (int k0 = 0; k0 < K; k0 += BK) {
#pragma unroll
        for (int i = 0; i < (BM * BK / 8) / 256; ++i) {
            int idx = (i * 256 + tid) * 8;
            int m = idx >> 6, kk = idx & 63;
            *(bf16x8*)&Asl[m * PK + kk] =
                *(const bf16x8*)&A[(size_t)(m0 + m) * K + k0 + kk];
        }
#pragma unroll
        for (int i = 0; i < (BN * BK / 8) / 256; ++i) {
            int idx = (i * 256 + tid) * 8;
            int n = idx >> 6, kk = idx & 63;
            *(bf16x8*)&Bsl[n * PK + kk] =
                *(const bf16x8*)&B[(size_t)(n0 + n) * K + k0 + kk];
        }
        __syncthreads();
#pragma unroll
        for (int ks = 0; ks < 2; ++ks) {
            bf16x8 af[4], bf[NI];
#pragma unroll
            for (int mi = 0; mi < 4; ++mi)
                af[mi] = *(const bf16x8*)&Asl[(wm + mi * 16 + l16) * PK + ks * 32 + quad * 8];
#pragma unroll
            for (int ni = 0; ni < NI; ++ni)
                bf[ni] = *(const bf16x8*)&Bsl[(wn + ni * 16 + l16) * PK + ks * 32 + quad * 8];
#pragma unroll
            for (int mi = 0; mi < 4; ++mi)
#pragma unroll
                for (int ni = 0; ni < NI; ++ni)
                    acc[mi][ni] = __builtin_amdgcn_mfma_f32_16x16x32_bf16(
                        af[mi], bf[ni], acc[mi][ni], 0, 0, 0);
        }
        __syncthreads();
    }

#pragma unroll
    for (int mi = 0; mi < 4; ++mi)
#pragma unroll
        for (int r = 0; r < 4; ++r) {
            int row = m0 + wm + mi * 16 + quad * 4 + r;
#pragma unroll
            for (int ni = 0; ni < NI; ++ni) {
                int col = n0 + wn + ni * 16 + l16;
                float v = acc[mi][ni][r];
                if (bias) v += bias[col];
                C[(size_t)row * N + col] = (OutT)v;
            }
        }
}

// ---------------------------------------------------------------------------
// Split-K MFMA GEMM (fp32 partials, no bias).  (validated)
// ---------------------------------------------------------------------------
template <int BN>
__global__ void __launch_bounds__(256)
mgemm_sk(const __bf16* __restrict__ A, const __bf16* __restrict__ B,
         float* __restrict__ P, int N, int K, int KC, size_t mn)
{
    constexpr int BM = 128, BK = 64;
    constexpr int PK = BK + 8;
    constexpr int NI = BN / 32;
    __shared__ __bf16 Asl[BM * PK];
    __shared__ __bf16 Bsl[BN * PK];

    const int tid  = threadIdx.x;
    const int w    = tid >> 6, lane = tid & 63;
    const int quad = lane >> 4, l16 = lane & 15;
    const int wm   = (w >> 1) * 64, wn = (w & 1) * (BN / 2);
    const int m0   = blockIdx.x * BM, n0 = blockIdx.y * BN;
    const int kbeg = blockIdx.z * KC;

    floatx4 acc[4][NI];
#pragma unroll
    for (int mi = 0; mi < 4; ++mi)
#pragma unroll
        for (int ni = 0; ni < NI; ++ni)
            acc[mi][ni] = (floatx4){0.f, 0.f, 0.f, 0.f};

    for (int k0 = kbeg; k0 < kbeg + KC; k0 += BK) {
#pragma unroll
        for (int i = 0; i < (BM * BK / 8) / 256; ++i) {
            int idx = (i * 256 + tid) * 8;
            int m = idx >> 6, kk = idx & 63;
            *(bf16x8*)&Asl[m * PK + kk] =
                *(const bf16x8*)&A[(size_t)(m0 + m) * K + k0 + kk];
        }
#pragma unroll
        for (int i = 0; i < (BN * BK / 8) / 256; ++i) {
            int idx = (i * 256 + tid) * 8;
            int n = idx >> 6, kk = idx & 63;
            *(bf16x8*)&Bsl[n * PK + kk] =
                *(const bf16x8*)&B[(size_t)(n0 + n) * K + k0 + kk];
        }
        __syncthreads();
#pragma unroll
        for (int ks = 0; ks < 2; ++ks) {
            bf16x8 af[4], bf[NI];
#pragma unroll
            for (int mi = 0; mi < 4; ++mi)
                af[mi] = *(const bf16x8*)&Asl[(wm + mi * 16 + l16) * PK + ks * 32 + quad * 8];
#pragma unroll
            for (int ni = 0; ni < NI; ++ni)
                bf[ni] = *(const bf16x8*)&Bsl[(wn + ni * 16 + l16) * PK + ks * 32 + quad * 8];
#pragma unroll
            for (int mi = 0; mi < 4; ++mi)
#pragma unroll
                for (int ni = 0; ni < NI; ++ni)
                    acc[mi][ni] = __builtin_amdgcn_mfma_f32_16x16x32_bf16(
                        af[mi], bf[ni], acc[mi][ni], 0, 0, 0);
        }
        __syncthreads();
    }

    float* Pz = P + (size_t)blockIdx.z * mn;
#pragma unroll
    for (int mi = 0; mi < 4; ++mi)
#pragma unroll
        for (int r = 0; r < 4; ++r) {
            int row = m0 + wm + mi * 16 + quad * 4 + r;
#pragma unroll
            for (int ni = 0; ni < NI; ++ni) {
                int col = n0 + wn + ni * 16 + l16;
                Pz[(size_t)row * N + col] = acc[mi][ni][r];
            }
        }
}

// ---------------------------------------------------------------------------
// Split-K reduce: out[i] = bf16( sum_z P[z*mn + i] + bias[i & nmask] ).
// ---------------------------------------------------------------------------
__global__ void __launch_bounds__(256)
sk_reduce(const float* __restrict__ P, const float* __restrict__ bias,
          __bf16* __restrict__ out, size_t mn, int nsplit, int nmask)
{
    const size_t i = ((size_t)blockIdx.x * 256 + threadIdx.x) * 4;
    if (i >= mn) return;
    float4 s = *(const float4*)(P + i);
    for (int z = 1; z < nsplit; ++z) {
        float4 t = *(const float4*)(P + (size_t)z * mn + i);
        s.x += t.x; s.y += t.y; s.z += t.z; s.w += t.w;
    }
    if (bias) {
        const int c = (int)(i & (size_t)nmask);
        s.x += bias[c]; s.y += bias[c + 1]; s.z += bias[c + 2]; s.w += bias[c + 3];
    }
    bf16x4 o = { (__bf16)s.x, (__bf16)s.y, (__bf16)s.z, (__bf16)s.w };
    *(bf16x4*)(out + i) = o;
}

// ---------------------------------------------------------------------------
// In-place LayerNorm(C=512) + exact GELU on bf16 data, fp32 params.
// ---------------------------------------------------------------------------
__global__ void __launch_bounds__(256)
ln_gelu(bf16* __restrict__ data, const float* __restrict__ w, const float* __restrict__ bp)
{
    __shared__ float red[256];
    const int tid = threadIdx.x;
    const size_t base = (size_t)blockIdx.x * 512;
    float x0 = b2f(data[base + tid]);
    float x1 = b2f(data[base + 256 + tid]);

    red[tid] = x0 + x1;
    __syncthreads();
#pragma unroll
    for (int off = 128; off > 0; off >>= 1) {
        if (tid < off) red[tid] += red[tid + off];
        __syncthreads();
    }
    float mu = red[0] * (1.0f / 512.0f);
    __syncthreads();

    float d0 = x0 - mu, d1 = x1 - mu;
    red[tid] = d0 * d0 + d1 * d1;
    __syncthreads();
#pragma unroll
    for (int off = 128; off > 0; off >>= 1) {
        if (tid < off) red[tid] += red[tid + off];
        __syncthreads();
    }
    float rstd = rsqrtf(red[0] * (1.0f / 512.0f) + 1e-5f);

    float y0 = d0 * rstd * w[tid] + bp[tid];
    float y1 = d1 * rstd * w[256 + tid] + bp[256 + tid];
    y0 = 0.5f * y0 * (1.0f + erff(y0 * 0.70710678118654752f));
    y1 = 0.5f * y1 * (1.0f + erff(y1 * 0.70710678118654752f));
    data[base + tid]       = f2b(y0);
    data[base + 256 + tid] = f2b(y1);
}

// ---------------------------------------------------------------------------
// v + depthwise 3x3 (pad 1) residual, layout (B*hw, 256). bf16 data, fp32 wts.
// ---------------------------------------------------------------------------
__global__ void __launch_bounds__(256)
local_res(const bf16* __restrict__ v, const float* __restrict__ lw,
          const float* __restrict__ lb, bf16* __restrict__ outp,
          int hw_bits, int w1_bits)
{
    const int idx = blockIdx.x * 256 + threadIdx.x;
    const int c   = idx & 255;
    const int pix = (idx >> 8) & ((1 << hw_bits) - 1);
    const int b   = idx >> (8 + hw_bits);
    const int w1  = 1 << w1_bits;
    const int h1  = 1 << (hw_bits - w1_bits);
    const int y = pix >> w1_bits, x = pix & (w1 - 1);

    float acc = b2f(v[idx]) + lb[c];
#pragma unroll
    for (int ky = 0; ky < 3; ++ky) {
        int yy = y + ky - 1;
        if (yy < 0 || yy >= h1) continue;
#pragma unroll
        for (int kx = 0; kx < 3; ++kx) {
            int xx = x + kx - 1;
            if (xx < 0 || xx >= w1) continue;
            acc += lw[c * 9 + ky * 3 + kx] *
                   b2f(v[(((b << hw_bits) + (yy << w1_bits) + xx) << 8) + c]);
        }
    }
    outp[idx] = f2b(acc);
}

// ---------------------------------------------------------------------------
// V transpose: in (b*Nk + j, 256) -> out (b*256 + c)*Nk + j.  (validated R5)
// ---------------------------------------------------------------------------
__global__ void __launch_bounds__(256)
vtrans(const __bf16* __restrict__ in, __bf16* __restrict__ out, int Nk)
{
    __shared__ __bf16 t[64][72];
    const int jt = blockIdx.x, cg = blockIdx.y, b = blockIdx.z;
    const int tid = threadIdx.x;
    const int chunk = tid & 7;

#pragma unroll
    for (int i = 0; i < 2; ++i) {
        int jr = i * 32 + (tid >> 3);
        bf16x8 v = *(const bf16x8*)(in + ((size_t)(b * Nk + jt * 64 + jr) << 8)
                                       + cg * 64 + chunk * 8);
        int ch = chunk ^ ((jr >> 3) & 7);
        *(bf16x8*)&t[jr][ch * 8] = v;
    }
    __syncthreads();

#pragma unroll
    for (int i = 0; i < 2; ++i) {
        int cr = i * 32 + (tid >> 3);
        int jc = tid & 7;
        bf16x8 o;
#pragma unroll
        for (int u = 0; u < 8; ++u) {
            int j  = jc * 8 + u;
            int ch = (cr >> 3) ^ ((j >> 3) & 7);
            o[u] = t[j][ch * 8 + (cr & 7)];
        }
        *(bf16x8*)(out + (size_t)(b * 256 + cg * 64 + cr) * Nk + jt * 64 + jc * 8) = o;
    }
}

// ---------------------------------------------------------------------------
// MFMA attention v2 (validated R5): pre-transposed V, LDS-staged K+V^T,
// register prefetch of the next tile.
// ---------------------------------------------------------------------------
__global__ void __launch_bounds__(256)
attn_mfma(const bf16* __restrict__ qmat, const bf16* __restrict__ kmat,
          const bf16* __restrict__ vtmat, bf16* __restrict__ x,
          int Nk, int hoff, int xoff)
{
    __shared__ __bf16 lds_k[32][72];
    __shared__ __bf16 lds_vt[64][40];
    __shared__ __bf16 lds_p[4][16][40];

    const int bid = blockIdx.x;
    const int qt = bid & 15;
    const int h  = (bid >> 4) & 3;
    const int b  = bid >> 6;
    const int tid = threadIdx.x;
    const int w = tid >> 6, lane = tid & 63;
    const int quad = lane >> 4, l16 = lane & 15;

    const int qrow = b * 1024 + qt * 64 + w * 16 + l16;
    const __bf16* qp = (const __bf16*)qmat + (size_t)qrow * 512 + (hoff + h) * 64 + quad * 8;
    const bf16x8 qf0 = *(const bf16x8*)qp;
    const bf16x8 qf1 = *(const bf16x8*)(qp + 32);

    const __bf16* ksrc = (const __bf16*)kmat + ((size_t)b * Nk << 8)
                         + (size_t)(tid >> 3) * 256 + h * 64 + (tid & 7) * 8;
    const __bf16* vsrc = (const __bf16*)vtmat
                         + (size_t)(b * 256 + h * 64 + (tid >> 2)) * Nk + (tid & 3) * 8;

    bf16x8 kreg = *(const bf16x8*)ksrc;
    bf16x8 vreg = *(const bf16x8*)vsrc;

    floatx4 acc_o[4];
#pragma unroll
    for (int nt = 0; nt < 4; ++nt) acc_o[nt] = (floatx4){0.f, 0.f, 0.f, 0.f};
    float rs[4] = {0.f, 0.f, 0.f, 0.f};

    for (int j0 = 0; j0 < Nk; j0 += 32) {
        __syncthreads();
        *(bf16x8*)&lds_k[tid >> 3][(tid & 7) * 8] = kreg;
        *(bf16x8*)&lds_vt[tid >> 2][(tid & 3) * 8] = vreg;
        __syncthreads();
        if (j0 + 32 < Nk) {
            kreg = *(const bf16x8*)(ksrc + ((size_t)(j0 + 32) << 8));
            vreg = *(const bf16x8*)(vsrc + j0 + 32);
        }

#pragma unroll
        for (int jh = 0; jh < 2; ++jh) {
            const __bf16* kp = &lds_k[jh * 16 + l16][quad * 8];
            bf16x8 kf0 = *(const bf16x8*)kp;
            bf16x8 kf1 = *(const bf16x8*)(kp + 32);
            floatx4 s = (floatx4){0.f, 0.f, 0.f, 0.f};
            s = __builtin_amdgcn_mfma_f32_16x16x32_bf16(qf0, kf0, s, 0, 0, 0);
            s = __builtin_amdgcn_mfma_f32_16x16x32_bf16(qf1, kf1, s, 0, 0, 0);
#pragma unroll
            for (int r = 0; r < 4; ++r) {
                float p = __expf(s[r] * 0.125f);
                rs[r] += p;
                lds_p[w][quad * 4 + r][jh * 16 + l16] = (__bf16)p;
            }
        }
        bf16x8 pf = *(const bf16x8*)&lds_p[w][l16][quad * 8];
#pragma unroll
        for (int nt = 0; nt < 4; ++nt) {
            bf16x8 vf = *(const bf16x8*)&lds_vt[nt * 16 + l16][quad * 8];
            acc_o[nt] = __builtin_amdgcn_mfma_f32_16x16x32_bf16(pf, vf, acc_o[nt], 0, 0, 0);
        }
    }

#pragma unroll
    for (int r = 0; r < 4; ++r) {
        float v = rs[r];
        v += __shfl_xor(v, 1);
        v += __shfl_xor(v, 2);
        v += __shfl_xor(v, 4);
        v += __shfl_xor(v, 8);
        rs[r] = v;
    }

    const int mg = qt * 64 + w * 16 + quad * 4;
#pragma unroll
    for (int r = 0; r < 4; ++r) {
        const float inv = 1.0f / rs[r];
        __bf16* xr = (__bf16*)x + (size_t)(b * 1024 + mg + r) * 512 + xoff + h * 64;
#pragma unroll
        for (int nt = 0; nt < 4; ++nt)
            xr[nt * 16 + l16] = (__bf16)(acc_o[nt][r] * inv);
    }
}

// ---------------------------------------------------------------------------
extern "C" void kernel_launch(void* const* d_in, const int* in_sizes, int n_in,
                              void* d_out, int out_size, void* d_ws, size_t ws_size,
                              hipStream_t stream)
{
    const float* query   = (const float*)d_in[0];
    const float* key     = (const float*)d_in[1];
    const float* value   = (const float*)d_in[2];
    const float* q_w     = (const float*)d_in[5];
    const float* sr1_w   = (const float*)d_in[6];
    const float* sr1_b   = (const float*)d_in[7];
    const float* norm1_w = (const float*)d_in[8];
    const float* norm1_b = (const float*)d_in[9];
    const float* sr2_w   = (const float*)d_in[10];
    const float* sr2_b   = (const float*)d_in[11];
    const float* norm2_w = (const float*)d_in[12];
    const float* norm2_b = (const float*)d_in[13];
    const float* k1_w    = (const float*)d_in[14];
    /* v1_w = d_in[15] unused: reference (faithfully) uses k1_w for v1 */
    const float* k2_w    = (const float*)d_in[16];
    const float* v2_w    = (const float*)d_in[17];
    const float* lc1_w   = (const float*)d_in[18];
    const float* lc1_b   = (const float*)d_in[19];
    const float* lc2_w   = (const float*)d_in[20];
    const float* lc2_b   = (const float*)d_in[21];
    const float* proj_w  = (const float*)d_in[22];
    const float* proj_b  = (const float*)d_in[23];
    float* out = (float*)d_out;

    // ---- workspace map (MiB offsets), peak ~116 MiB -----------------------
    char* base = (char*)d_ws;
    const size_t MiB = 1024 * 1024;
    __bf16* S     = (__bf16*)(base + 0 * MiB);    // 64 MiB: im2col scratch, then:
    __bf16* qproj = S;                            //   S+0  : 16 MiB (16384x512)
    __bf16* k1    = (__bf16*)(base + 16 * MiB);   //   S+16 :  2 MiB (4096x256)
    __bf16* v1    = (__bf16*)(base + 18 * MiB);   //   S+18 :  2 MiB
    __bf16* k2    = (__bf16*)(base + 20 * MiB);   //   S+20 :  8 MiB (16384x256)
    __bf16* v2    = (__bf16*)(base + 28 * MiB);   //   S+28 :  8 MiB
    __bf16* qbf   = (__bf16*)(base + 36 * MiB);   //   S+36 : 16 MiB (query bf16;
                                                  //   dead after q-proj GEMM)
    __bf16* vt2   = (__bf16*)(base + 36 * MiB);   //   reuse: 8 MiB V2^T
    __bf16* vt1   = (__bf16*)(base + 44 * MiB);   //   reuse: 2 MiB V1^T
    __bf16* c1k   = (__bf16*)(base + 64 * MiB);   //  4 MiB (4096x512)
    __bf16* c1v   = (__bf16*)(base + 68 * MiB);   //  4 MiB
    __bf16* c2k   = (__bf16*)(base + 72 * MiB);   // 16 MiB (16384x512)
    __bf16* c2v   = (__bf16*)(base + 88 * MiB);   // 16 MiB
    float*  skp   = (float*)(base + 72 * MiB);    // 32 MiB: split-K partials
    __bf16* wq    = (__bf16*)(base + 104 * MiB);  // 0.5 MiB (512x512)
    __bf16* wsr1  = (__bf16*)(base + 104 * MiB + 524288);            // 8 MiB
    __bf16* wsr2  = (__bf16*)(base + 112 * MiB + 524288);            // 2 MiB
    __bf16* wk1   = (__bf16*)(base + 114 * MiB + 524288);            // 0.25
    __bf16* wk2   = (__bf16*)(base + 114 * MiB + 786432);            // 0.25
    __bf16* wv2   = (__bf16*)(base + 115 * MiB);                     // 0.25
    __bf16* wproj = (__bf16*)(base + 115 * MiB + 262144);            // 0.5
    __bf16* v1r   = c1k;   // alias: c1k dead after k1 head-proj
    __bf16* v2r   = c2v;   // alias: c2v dead after v2 head-proj
    __bf16* xbuf  = c2k;   // alias: c2k dead after k2 head-proj

    dim3 blk(256);

    // 1) weights -> bf16 (one launch)
    {
        DcPack p;
        p.e[0] = { q_w,    wq,    512 * 512 };
        p.e[1] = { sr1_w,  wsr1,  512 * 8192 };
        p.e[2] = { sr2_w,  wsr2,  512 * 2048 };
        p.e[3] = { k1_w,   wk1,   256 * 512 };
        p.e[4] = { k2_w,   wk2,   256 * 512 };
        p.e[5] = { v2_w,   wv2,   256 * 512 };
        p.e[6] = { proj_w, wproj, 512 * 512 };
        p.e[7] = { nullptr, nullptr, 0 };
        int maxb = (512 * 8192 / 4 + 255) / 256;
        downcast_all<<<dim3(maxb, 7), blk, 0, stream>>>(p, 7);
    }

    // 2) convs: source-coalesced im2col + MFMA GEMM (split-K for sr1).
    const size_t mn1 = 4096 * 512;
    im2col_sr1<<<dim3(4096), blk, 0, stream>>>(key, S);
    mgemm_sk<64><<<dim3(32, 8, 4), blk, 0, stream>>>(S, wsr1, skp, 512, 8192, 2048, mn1);
    sk_reduce<<<dim3(mn1 / 1024), blk, 0, stream>>>(skp, sr1_b, c1k, mn1, 4, 511);
    im2col_sr1<<<dim3(4096), blk, 0, stream>>>(value, S);
    mgemm_sk<64><<<dim3(32, 8, 4), blk, 0, stream>>>(S, wsr1, skp, 512, 8192, 2048, mn1);
    sk_reduce<<<dim3(mn1 / 1024), blk, 0, stream>>>(skp, sr1_b, c1v, mn1, 4, 511);
    im2col_sr2<<<dim3(1024), blk, 0, stream>>>(key, S);
    mgemm<64, __bf16><<<dim3(128, 8), blk, 0, stream>>>(S, wsr2, sr2_b, c2k, 512, 2048);
    im2col_sr2<<<dim3(1024), blk, 0, stream>>>(value, S);
    mgemm<64, __bf16><<<dim3(128, 8), blk, 0, stream>>>(S, wsr2, sr2_b, c2v, 512, 2048);

    // 3) query -> bf16, then q projection (into S, now free).
    {
        DcPack p;
        p.e[0] = { query, qbf, 16384 * 512 };
        downcast_all<<<dim3(16384 * 512 / 1024, 1), blk, 0, stream>>>(p, 1);
    }
    mgemm<64, __bf16><<<dim3(128, 8), blk, 0, stream>>>(qbf, wq, nullptr, qproj, 512, 512);

    // 4) LayerNorm + GELU (in place)
    ln_gelu<<<dim3(4096),  blk, 0, stream>>>((bf16*)c1k, norm1_w, norm1_b);
    ln_gelu<<<dim3(4096),  blk, 0, stream>>>((bf16*)c1v, norm1_w, norm1_b);
    ln_gelu<<<dim3(16384), blk, 0, stream>>>((bf16*)c2k, norm2_w, norm2_b);
    ln_gelu<<<dim3(16384), blk, 0, stream>>>((bf16*)c2v, norm2_w, norm2_b);

    // 5) head projections (v1 uses k1_w — faithful to source)
    mgemm<64, __bf16><<<dim3(32, 4),  blk, 0, stream>>>(c1k, wk1, nullptr, k1, 256, 512);
    mgemm<64, __bf16><<<dim3(32, 4),  blk, 0, stream>>>(c1v, wk1, nullptr, v1, 256, 512);
    mgemm<64, __bf16><<<dim3(128, 4), blk, 0, stream>>>(c2k, wk2, nullptr, k2, 256, 512);
    mgemm<64, __bf16><<<dim3(128, 4), blk, 0, stream>>>(c2v, wv2, nullptr, v2, 256, 512);

    // 6) depthwise 3x3 residual, then V -> V^T for the attention PV step
    local_res<<<dim3(4096),  blk, 0, stream>>>((bf16*)v1, lc1_w, lc1_b, (bf16*)v1r, 8, 4);
    local_res<<<dim3(16384), blk, 0, stream>>>((bf16*)v2, lc2_w, lc2_b, (bf16*)v2r, 10, 5);
    vtrans<<<dim3(4, 4, 16),  blk, 0, stream>>>(v1r, vt1, 256);
    vtrans<<<dim3(16, 4, 16), blk, 0, stream>>>(v2r, vt2, 1024);

    // 7) MFMA attention (K + pre-transposed V^T, LDS-staged, prefetched)
    attn_mfma<<<dim3(1024), blk, 0, stream>>>((bf16*)qproj, (bf16*)k1, (bf16*)vt1,
                                              (bf16*)xbuf, 256, 0, 0);
    attn_mfma<<<dim3(1024), blk, 0, stream>>>((bf16*)qproj, (bf16*)k2, (bf16*)vt2,
                                              (bf16*)xbuf, 1024, 4, 256);

    // 8) out = x @ proj_w^T + proj_b (fp32 out)
    mgemm<64, float><<<dim3(128, 8), blk, 0, stream>>>(xbuf, wproj, proj_b, out, 512, 512);
}